// Round 1
// baseline (596.936 us; speedup 1.0000x reference)
//
#include <hip/hip_runtime.h>
#include <math.h>

// Problem constants (reference file)
#define IN_C 128      // input channels
#define HC   128      // H * OUT_C
#define OUT_C 64
#define NEG_SLOPE 0.2f
#define LN_EPS 1e-5f

// ---------------------------------------------------------------------------
// K_V: fold att_edge into W_edge:  V[d][h] = sum_c W_edge[d, h*64+c]*att_edge[h,c]
// ---------------------------------------------------------------------------
__global__ void k_fold_edge(const float* __restrict__ W_edge,
                            const float* __restrict__ att_edge,
                            float* __restrict__ V) {
    int t = threadIdx.x;
    if (t < 8) {
        int d = t >> 1, h = t & 1;
        float s = 0.f;
        for (int c = 0; c < 64; ++c)
            s += W_edge[d * HC + h * 64 + c] * att_edge[h * 64 + c];
        V[d * 2 + h] = s;   // layout V[d][h]
    }
}

// ---------------------------------------------------------------------------
// K1: h = x @ W   (M x 128) = (M x 128)(128 x 128), fp32 register-tiled.
// Block: 256 threads, 64 rows x 128 cols. Thread: 8 rows x 4 cols.
// x tile transposed in LDS (stride 68 floats -> 16B-aligned b128 reads,
// broadcast across half-wave). W streamed from global (L2-resident, 64 KB).
// ---------------------------------------------------------------------------
__global__ __launch_bounds__(256) void k_gemm_h(const float* __restrict__ x,
                                                const float* __restrict__ W,
                                                float* __restrict__ h, int M) {
    __shared__ float xT[128 * 68];
    const int t = threadIdx.x;
    const int brow = blockIdx.x * 64;
    const float4* x4 = (const float4*)x;

    #pragma unroll
    for (int i = 0; i < 8; ++i) {
        int idx = i * 256 + t;
        int r = idx >> 5, cg = idx & 31;
        int row = brow + r;
        float4 v = make_float4(0.f, 0.f, 0.f, 0.f);
        if (row < M) v = x4[(size_t)row * 32 + cg];
        int k0 = cg * 4;
        xT[(k0 + 0) * 68 + r] = v.x;
        xT[(k0 + 1) * 68 + r] = v.y;
        xT[(k0 + 2) * 68 + r] = v.z;
        xT[(k0 + 3) * 68 + r] = v.w;
    }
    __syncthreads();

    const int tx = t & 31, ty = t >> 5;
    float acc[8][4];
    #pragma unroll
    for (int j = 0; j < 8; ++j)
        #pragma unroll
        for (int c = 0; c < 4; ++c) acc[j][c] = 0.f;

    const float4* W4 = (const float4*)W;
    #pragma unroll 4
    for (int k = 0; k < 128; ++k) {
        float4 w4 = W4[k * 32 + tx];
        float xr[8];
        #pragma unroll
        for (int j = 0; j < 8; ++j) xr[j] = xT[k * 68 + ty * 8 + j];
        #pragma unroll
        for (int j = 0; j < 8; ++j) {
            acc[j][0] += xr[j] * w4.x;
            acc[j][1] += xr[j] * w4.y;
            acc[j][2] += xr[j] * w4.z;
            acc[j][3] += xr[j] * w4.w;
        }
    }

    #pragma unroll
    for (int j = 0; j < 8; ++j) {
        int row = brow + ty * 8 + j;
        if (row < M) {
            float4 o = make_float4(acc[j][0], acc[j][1], acc[j][2], acc[j][3]);
            ((float4*)h)[(size_t)row * 32 + tx] = o;
        }
    }
}

// ---------------------------------------------------------------------------
// K2: per-node attention logits  a_src[n,h], a_dst[n,h]  (wave per node)
// ---------------------------------------------------------------------------
__global__ __launch_bounds__(256) void k_attn_nodes(const float* __restrict__ h,
                                                    const float* __restrict__ attS,
                                                    const float* __restrict__ attD,
                                                    float* __restrict__ a_src,
                                                    float* __restrict__ a_dst, int M) {
    int w = threadIdx.x >> 6, lane = threadIdx.x & 63;
    int n = blockIdx.x * 4 + w;
    if (n >= M) return;
    const float* hr = h + (size_t)n * HC;
    float h0 = hr[lane], h1 = hr[64 + lane];
    float s0 = h0 * attS[lane], s1 = h1 * attS[64 + lane];
    float d0 = h0 * attD[lane], d1 = h1 * attD[64 + lane];
    #pragma unroll
    for (int m = 32; m; m >>= 1) {
        s0 += __shfl_xor(s0, m);
        s1 += __shfl_xor(s1, m);
        d0 += __shfl_xor(d0, m);
        d1 += __shfl_xor(d1, m);
    }
    if (lane == 0) {
        ((float2*)a_src)[n] = make_float2(s0, s1);
        ((float2*)a_dst)[n] = make_float2(d0, d1);
    }
}

// ---------------------------------------------------------------------------
// K3: per-edge pass 1: alpha -> ex = exp(alpha) (no max subtraction; alpha is
// bounded ~|7| so fp32-exact enough), accumulate denom per dst, count per dst.
// ---------------------------------------------------------------------------
__global__ __launch_bounds__(256) void k_edge1(const int* __restrict__ ei,
                                               const float* __restrict__ ea,
                                               const float* __restrict__ a_src,
                                               const float* __restrict__ a_dst,
                                               const float* __restrict__ V,
                                               float* __restrict__ ex,
                                               float* __restrict__ denom,
                                               int* __restrict__ count, int E) {
    int e = blockIdx.x * 256 + threadIdx.x;
    if (e >= E) return;
    int s = ei[e], d = ei[E + e];
    float4 a = ((const float4*)ea)[e];
    float ae0 = a.x * V[0] + a.y * V[2] + a.z * V[4] + a.w * V[6];
    float ae1 = a.x * V[1] + a.y * V[3] + a.z * V[5] + a.w * V[7];
    float2 as = ((const float2*)a_src)[s];
    float2 ad = ((const float2*)a_dst)[d];
    float al0 = as.x + ad.x + ae0; al0 = al0 > 0.f ? al0 : NEG_SLOPE * al0;
    float al1 = as.y + ad.y + ae1; al1 = al1 > 0.f ? al1 : NEG_SLOPE * al1;
    float e0 = __expf(al0), e1 = __expf(al1);
    ((float2*)ex)[e] = make_float2(e0, e1);
    atomicAdd(&denom[2 * d + 0], e0);
    atomicAdd(&denom[2 * d + 1], e1);
    atomicAdd(&count[d], 1);
}

// ---------------------------------------------------------------------------
// K4a/b/c: exclusive scan of count[] -> rowptr[], cursor[]  (256-chunk scan)
// ---------------------------------------------------------------------------
__global__ __launch_bounds__(256) void k_scan_a(const int* __restrict__ count,
                                                int* __restrict__ incl,
                                                int* __restrict__ bsum, int n) {
    __shared__ int sm[256];
    int t = threadIdx.x, i = blockIdx.x * 256 + t;
    int v = (i < n) ? count[i] : 0;
    sm[t] = v;
    __syncthreads();
    for (int off = 1; off < 256; off <<= 1) {
        int u = (t >= off) ? sm[t - off] : 0;
        __syncthreads();
        sm[t] += u;
        __syncthreads();
    }
    if (i < n) incl[i] = sm[t];
    if (t == 255) bsum[blockIdx.x] = sm[255];
}

__global__ __launch_bounds__(512) void k_scan_b(int* __restrict__ bsum, int nb) {
    __shared__ int sm[512];
    int t = threadIdx.x;
    int v = (t < nb) ? bsum[t] : 0;
    sm[t] = v;
    __syncthreads();
    for (int off = 1; off < 512; off <<= 1) {
        int u = (t >= off) ? sm[t - off] : 0;
        __syncthreads();
        sm[t] += u;
        __syncthreads();
    }
    if (t < nb) bsum[t] = sm[t] - v;   // exclusive block offsets
}

__global__ __launch_bounds__(256) void k_scan_c(const int* __restrict__ count,
                                                const int* __restrict__ incl,
                                                const int* __restrict__ bsum,
                                                int* __restrict__ rowptr,
                                                int* __restrict__ cursor, int n) {
    int i = blockIdx.x * 256 + threadIdx.x;
    if (i >= n) return;
    int r = bsum[blockIdx.x] + incl[i] - count[i];
    rowptr[i] = r;
    cursor[i] = r;
    if (i == n - 1) rowptr[n] = bsum[blockIdx.x] + incl[i];
}

// ---------------------------------------------------------------------------
// K5: per-edge pass 2: scatter payload {src, ex0, ex1} into CSR slots.
// ---------------------------------------------------------------------------
__global__ __launch_bounds__(256) void k_edge2(const int* __restrict__ ei,
                                               const float* __restrict__ ex,
                                               int* __restrict__ cursor,
                                               float4* __restrict__ payload, int E) {
    int e = blockIdx.x * 256 + threadIdx.x;
    if (e >= E) return;
    int d = ei[E + e];
    int pos = atomicAdd(&cursor[d], 1);
    float2 x2 = ((const float2*)ex)[e];
    payload[pos] = make_float4(__int_as_float(ei[e]), x2.x, x2.y, 0.f);
}

// ---------------------------------------------------------------------------
// K6: gather per node (wave per node, lane = channel), head-mean + bias +
// LayerNorm (64-lane shuffle reduce) + ReLU, write final out.
// ---------------------------------------------------------------------------
__global__ __launch_bounds__(256) void k_gather(const float4* __restrict__ payload,
                                                const int* __restrict__ rowptr,
                                                const float* __restrict__ denom,
                                                const float* __restrict__ h,
                                                const float* __restrict__ bias,
                                                const float* __restrict__ gamma,
                                                const float* __restrict__ beta,
                                                float* __restrict__ out, int M) {
    int w = threadIdx.x >> 6, lane = threadIdx.x & 63;
    int n = blockIdx.x * 4 + w;
    if (n >= M) return;
    int beg = rowptr[n], end = rowptr[n + 1];
    float d0 = denom[2 * n + 0] + 1e-16f;
    float d1 = denom[2 * n + 1] + 1e-16f;
    float acc0 = 0.f, acc1 = 0.f;
    for (int i = beg; i < end; ++i) {
        float4 p = payload[i];
        int s = __float_as_int(p.x);
        const float* hr = h + (size_t)s * HC;
        acc0 += p.y * hr[lane];
        acc1 += p.z * hr[64 + lane];
    }
    float o = 0.5f * (acc0 / d0 + acc1 / d1) + bias[lane];
    // LayerNorm over 64 channels == exactly one wave
    float mu = o;
    #pragma unroll
    for (int m = 32; m; m >>= 1) mu += __shfl_xor(mu, m);
    mu *= (1.f / 64.f);
    float c = o - mu;
    float v = c * c;
    #pragma unroll
    for (int m = 32; m; m >>= 1) v += __shfl_xor(v, m);
    v *= (1.f / 64.f);
    float y = c * rsqrtf(v + LN_EPS) * gamma[lane] + beta[lane];
    out[(size_t)n * OUT_C + lane] = fmaxf(y, 0.f);
}

// ---------------------------------------------------------------------------
extern "C" void kernel_launch(void* const* d_in, const int* in_sizes, int n_in,
                              void* d_out, int out_size, void* d_ws, size_t ws_size,
                              hipStream_t stream) {
    const float* x     = (const float*)d_in[0];
    const int*   ei    = (const int*)d_in[1];
    const float* ea    = (const float*)d_in[2];
    const float* W     = (const float*)d_in[3];
    const float* attS  = (const float*)d_in[4];
    const float* attD  = (const float*)d_in[5];
    const float* We    = (const float*)d_in[6];
    const float* attE  = (const float*)d_in[7];
    const float* bias  = (const float*)d_in[8];
    const float* gamma = (const float*)d_in[9];
    const float* beta  = (const float*)d_in[10];

    const int M = in_sizes[0] / IN_C;      // 100000
    const int E = in_sizes[1] / 2;         // 1600000
    const int nb1 = (M + 255) / 256;       // scan chunks (391 <= 512)

    // workspace carve-up (≈93 MB total)
    char* ws = (char*)d_ws;
    size_t off = 0;
    auto alloc = [&](size_t bytes) -> void* {
        void* p = ws + off;
        off += (bytes + 255) & ~(size_t)255;
        return p;
    };
    float* h       = (float*)alloc((size_t)M * HC * 4);
    float* a_src   = (float*)alloc((size_t)M * 2 * 4);
    float* a_dst   = (float*)alloc((size_t)M * 2 * 4);
    float* denom   = (float*)alloc((size_t)M * 2 * 4);
    int*   count   = (int*)  alloc((size_t)M * 4);
    int*   incl    = (int*)  alloc((size_t)M * 4);
    int*   bsum    = (int*)  alloc((size_t)nb1 * 4);
    int*   rowptr  = (int*)  alloc((size_t)(M + 1) * 4);
    int*   cursor  = (int*)  alloc((size_t)M * 4);
    float* ex      = (float*)alloc((size_t)E * 2 * 4);
    float4* payload= (float4*)alloc((size_t)E * 16);
    float* V       = (float*)alloc(32);

    hipMemsetAsync(denom, 0, (size_t)M * 2 * 4, stream);
    hipMemsetAsync(count, 0, (size_t)M * 4, stream);

    k_fold_edge<<<1, 64, 0, stream>>>(We, attE, V);
    k_gemm_h<<<(M + 63) / 64, 256, 0, stream>>>(x, W, h, M);
    k_attn_nodes<<<(M + 3) / 4, 256, 0, stream>>>(h, attS, attD, a_src, a_dst, M);
    k_edge1<<<(E + 255) / 256, 256, 0, stream>>>(ei, ea, a_src, a_dst, V, ex, denom, count, E);
    k_scan_a<<<nb1, 256, 0, stream>>>(count, incl, bsum, M);
    k_scan_b<<<1, 512, 0, stream>>>(bsum, nb1);
    k_scan_c<<<nb1, 256, 0, stream>>>(count, incl, bsum, rowptr, cursor, M);
    k_edge2<<<(E + 255) / 256, 256, 0, stream>>>(ei, ex, cursor, payload, E);
    k_gather<<<(M + 3) / 4, 256, 0, stream>>>(payload, rowptr, denom, h, bias, gamma, beta,
                                              (float*)d_out, M);
}

// Round 2
// 285.491 us; speedup vs baseline: 2.0909x; 2.0909x over previous
//
#include <hip/hip_runtime.h>
#include <hip/hip_fp16.h>
#include <math.h>

#define IN_C 128
#define HC   128
#define OUT_C 64
#define NEG_SLOPE 0.2f
#define LN_EPS 1e-5f

// round-to-nearest-even bf16 pack of two floats -> uint (a=low, b=high)
__device__ inline unsigned bf16pack(float a, float b) {
    unsigned ua = __float_as_uint(a), ub = __float_as_uint(b);
    ua = (ua + 0x7fffu + ((ua >> 16) & 1u)) >> 16;
    ub = (ub + 0x7fffu + ((ub >> 16) & 1u)) >> 16;
    return ua | (ub << 16);
}

// ---------------------------------------------------------------------------
// K_V: fold att_edge into W_edge:  V[d][h] = sum_c W_edge[d, h*64+c]*att_edge[h,c]
// ---------------------------------------------------------------------------
__global__ void k_fold_edge(const float* __restrict__ W_edge,
                            const float* __restrict__ att_edge,
                            float* __restrict__ V) {
    int t = threadIdx.x;
    if (t < 8) {
        int d = t >> 1, h = t & 1;
        float s = 0.f;
        for (int c = 0; c < 64; ++c)
            s += W_edge[d * HC + h * 64 + c] * att_edge[h * 64 + c];
        V[d * 2 + h] = s;
    }
}

// ---------------------------------------------------------------------------
// K1: h = x @ W (register-tiled fp32), FUSED epilogue:
//   - a_src[n,h], a_dst[n,h] via in-register 16-lane shuffle reduce
//   - h packed to bf16 pairs {head0[ch], head1[ch]} -> hb[n][64] uints
// No fp32 h array is ever materialized.
// ---------------------------------------------------------------------------
__global__ __launch_bounds__(256) void k_gemm_h(const float* __restrict__ x,
                                                const float* __restrict__ W,
                                                const float* __restrict__ attS,
                                                const float* __restrict__ attD,
                                                unsigned* __restrict__ hb,
                                                float* __restrict__ a_src,
                                                float* __restrict__ a_dst, int M) {
    __shared__ float xT[128 * 68];
    const int t = threadIdx.x;
    const int brow = blockIdx.x * 64;
    const float4* x4 = (const float4*)x;

    #pragma unroll
    for (int i = 0; i < 8; ++i) {
        int idx = i * 256 + t;
        int r = idx >> 5, cg = idx & 31;
        int row = brow + r;
        float4 v = make_float4(0.f, 0.f, 0.f, 0.f);
        if (row < M) v = x4[(size_t)row * 32 + cg];
        int k0 = cg * 4;
        xT[(k0 + 0) * 68 + r] = v.x;
        xT[(k0 + 1) * 68 + r] = v.y;
        xT[(k0 + 2) * 68 + r] = v.z;
        xT[(k0 + 3) * 68 + r] = v.w;
    }
    __syncthreads();

    const int tx = t & 31, ty = t >> 5;
    float acc[8][4];
    #pragma unroll
    for (int j = 0; j < 8; ++j)
        #pragma unroll
        for (int c = 0; c < 4; ++c) acc[j][c] = 0.f;

    const float4* W4 = (const float4*)W;
    #pragma unroll 4
    for (int k = 0; k < 128; ++k) {
        float4 w4 = W4[k * 32 + tx];
        float xr[8];
        #pragma unroll
        for (int j = 0; j < 8; ++j) xr[j] = xT[k * 68 + ty * 8 + j];
        #pragma unroll
        for (int j = 0; j < 8; ++j) {
            acc[j][0] += xr[j] * w4.x;
            acc[j][1] += xr[j] * w4.y;
            acc[j][2] += xr[j] * w4.z;
            acc[j][3] += xr[j] * w4.w;
        }
    }

    // fused attention logits + bf16 pack
    float as4[4], ad4[4];
    #pragma unroll
    for (int c = 0; c < 4; ++c) {
        as4[c] = attS[4 * tx + c];
        ad4[c] = attD[4 * tx + c];
    }

    #pragma unroll
    for (int j = 0; j < 8; ++j) {
        int row = brow + ty * 8 + j;
        float ps = 0.f, pd = 0.f;
        #pragma unroll
        for (int c = 0; c < 4; ++c) {
            ps += acc[j][c] * as4[c];
            pd += acc[j][c] * ad4[c];
        }
        // sum over 16-lane groups (head0: tx 0..15, head1: tx 16..31)
        #pragma unroll
        for (int m = 1; m < 16; m <<= 1) {
            ps += __shfl_xor(ps, m);
            pd += __shfl_xor(pd, m);
        }
        // partner exchange for bf16 pack: lane tx gets head1 (tx+16) values
        float p0 = __shfl_xor(acc[j][0], 16);
        float p1 = __shfl_xor(acc[j][1], 16);
        float p2 = __shfl_xor(acc[j][2], 16);
        float p3 = __shfl_xor(acc[j][3], 16);
        if (row < M) {
            if ((t & 15) == 0) {
                int head = (tx >> 4) & 1;
                a_src[2 * row + head] = ps;
                a_dst[2 * row + head] = pd;
            }
            if (tx < 16) {
                uint4 u;
                u.x = bf16pack(acc[j][0], p0);
                u.y = bf16pack(acc[j][1], p1);
                u.z = bf16pack(acc[j][2], p2);
                u.w = bf16pack(acc[j][3], p3);
                ((uint4*)hb)[(size_t)row * 16 + tx] = u;
            }
        }
    }
}

// ---------------------------------------------------------------------------
// K2: count pass — the ONLY atomic pass. Stores each edge's rank within its
// dst so the scatter pass needs no atomics.
// ---------------------------------------------------------------------------
__global__ __launch_bounds__(256) void k_count(const int* __restrict__ ei,
                                               int* __restrict__ count,
                                               int* __restrict__ pos, int E) {
    int e = blockIdx.x * 256 + threadIdx.x;
    if (e >= E) return;
    int d = ei[E + e];
    pos[e] = atomicAdd(&count[d], 1);
}

// ---------------------------------------------------------------------------
// K3a/b/c: exclusive scan of count[] -> rowptr[]
// ---------------------------------------------------------------------------
__global__ __launch_bounds__(256) void k_scan_a(const int* __restrict__ count,
                                                int* __restrict__ incl,
                                                int* __restrict__ bsum, int n) {
    __shared__ int sm[256];
    int t = threadIdx.x, i = blockIdx.x * 256 + t;
    int v = (i < n) ? count[i] : 0;
    sm[t] = v;
    __syncthreads();
    for (int off = 1; off < 256; off <<= 1) {
        int u = (t >= off) ? sm[t - off] : 0;
        __syncthreads();
        sm[t] += u;
        __syncthreads();
    }
    if (i < n) incl[i] = sm[t];
    if (t == 255) bsum[blockIdx.x] = sm[255];
}

__global__ __launch_bounds__(512) void k_scan_b(int* __restrict__ bsum, int nb) {
    __shared__ int sm[512];
    int t = threadIdx.x;
    int v = (t < nb) ? bsum[t] : 0;
    sm[t] = v;
    __syncthreads();
    for (int off = 1; off < 512; off <<= 1) {
        int u = (t >= off) ? sm[t - off] : 0;
        __syncthreads();
        sm[t] += u;
        __syncthreads();
    }
    if (t < nb) bsum[t] = sm[t] - v;
}

__global__ __launch_bounds__(256) void k_scan_c(const int* __restrict__ count,
                                                const int* __restrict__ incl,
                                                const int* __restrict__ bsum,
                                                int* __restrict__ rowptr, int n) {
    int i = blockIdx.x * 256 + threadIdx.x;
    if (i >= n) return;
    int r = bsum[blockIdx.x] + incl[i] - count[i];
    rowptr[i] = r;
    if (i == n - 1) rowptr[n] = bsum[blockIdx.x] + incl[i];
}

// ---------------------------------------------------------------------------
// K4: edge scatter — compute alpha/exp, write 8B payload {src, half2{e0,e1}}
// into CSR slot rowptr[d]+pos[e]. Zero atomics.
// ---------------------------------------------------------------------------
__global__ __launch_bounds__(256) void k_edge2(const int* __restrict__ ei,
                                               const float* __restrict__ ea,
                                               const float* __restrict__ a_src,
                                               const float* __restrict__ a_dst,
                                               const float* __restrict__ V,
                                               const int* __restrict__ rowptr,
                                               const int* __restrict__ pos,
                                               uint2* __restrict__ payload, int E) {
    int e = blockIdx.x * 256 + threadIdx.x;
    if (e >= E) return;
    int s = ei[e], d = ei[E + e];
    float4 a = ((const float4*)ea)[e];
    float ae0 = a.x * V[0] + a.y * V[2] + a.z * V[4] + a.w * V[6];
    float ae1 = a.x * V[1] + a.y * V[3] + a.z * V[5] + a.w * V[7];
    float2 as = ((const float2*)a_src)[s];
    float2 ad = ((const float2*)a_dst)[d];
    float al0 = as.x + ad.x + ae0; al0 = al0 > 0.f ? al0 : NEG_SLOPE * al0;
    float al1 = as.y + ad.y + ae1; al1 = al1 > 0.f ? al1 : NEG_SLOPE * al1;
    __half2 hx = __floats2half2_rn(__expf(al0), __expf(al1));
    int slot = rowptr[d] + pos[e];
    payload[slot] = make_uint2((unsigned)s, *reinterpret_cast<unsigned*>(&hx));
}

// ---------------------------------------------------------------------------
// K5: gather per node (wave per node, lane = channel), denominator computed
// in-loop (no atomics anywhere), head-mean + bias + LayerNorm + ReLU.
// ---------------------------------------------------------------------------
__global__ __launch_bounds__(256) void k_gather(const uint2* __restrict__ payload,
                                                const int* __restrict__ rowptr,
                                                const unsigned* __restrict__ hb,
                                                const float* __restrict__ bias,
                                                const float* __restrict__ gamma,
                                                const float* __restrict__ beta,
                                                float* __restrict__ out, int M) {
    int w = threadIdx.x >> 6, lane = threadIdx.x & 63;
    int n = blockIdx.x * 4 + w;
    if (n >= M) return;
    int beg = rowptr[n], end = rowptr[n + 1];
    float acc0 = 0.f, acc1 = 0.f, d0 = 0.f, d1 = 0.f;

    int i = beg;
    for (; i + 1 < end; i += 2) {
        uint2 pa = payload[i];
        uint2 pb = payload[i + 1];
        unsigned ha = hb[(size_t)pa.x * 64 + lane];
        unsigned hc = hb[(size_t)pb.x * 64 + lane];
        __half2 xa = *reinterpret_cast<const __half2*>(&pa.y);
        __half2 xb = *reinterpret_cast<const __half2*>(&pb.y);
        float ea0 = __low2float(xa), ea1 = __high2float(xa);
        float eb0 = __low2float(xb), eb1 = __high2float(xb);
        acc0 += ea0 * __uint_as_float(ha << 16);
        acc1 += ea1 * __uint_as_float(ha & 0xffff0000u);
        acc0 += eb0 * __uint_as_float(hc << 16);
        acc1 += eb1 * __uint_as_float(hc & 0xffff0000u);
        d0 += ea0 + eb0;
        d1 += ea1 + eb1;
    }
    if (i < end) {
        uint2 pa = payload[i];
        unsigned ha = hb[(size_t)pa.x * 64 + lane];
        __half2 xa = *reinterpret_cast<const __half2*>(&pa.y);
        float ea0 = __low2float(xa), ea1 = __high2float(xa);
        acc0 += ea0 * __uint_as_float(ha << 16);
        acc1 += ea1 * __uint_as_float(ha & 0xffff0000u);
        d0 += ea0;
        d1 += ea1;
    }

    float o = 0.5f * (acc0 / (d0 + 1e-16f) + acc1 / (d1 + 1e-16f)) + bias[lane];
    float mu = o;
    #pragma unroll
    for (int m = 32; m; m >>= 1) mu += __shfl_xor(mu, m);
    mu *= (1.f / 64.f);
    float c = o - mu;
    float v = c * c;
    #pragma unroll
    for (int m = 32; m; m >>= 1) v += __shfl_xor(v, m);
    v *= (1.f / 64.f);
    float y = c * rsqrtf(v + LN_EPS) * gamma[lane] + beta[lane];
    out[(size_t)n * OUT_C + lane] = fmaxf(y, 0.f);
}

// ---------------------------------------------------------------------------
extern "C" void kernel_launch(void* const* d_in, const int* in_sizes, int n_in,
                              void* d_out, int out_size, void* d_ws, size_t ws_size,
                              hipStream_t stream) {
    const float* x     = (const float*)d_in[0];
    const int*   ei    = (const int*)d_in[1];
    const float* ea    = (const float*)d_in[2];
    const float* W     = (const float*)d_in[3];
    const float* attS  = (const float*)d_in[4];
    const float* attD  = (const float*)d_in[5];
    const float* We    = (const float*)d_in[6];
    const float* attE  = (const float*)d_in[7];
    const float* bias  = (const float*)d_in[8];
    const float* gamma = (const float*)d_in[9];
    const float* beta  = (const float*)d_in[10];

    const int M = in_sizes[0] / IN_C;      // 100000
    const int E = in_sizes[1] / 2;         // 1600000
    const int nb1 = (M + 255) / 256;       // 391 <= 512

    char* ws = (char*)d_ws;
    size_t off = 0;
    auto alloc = [&](size_t bytes) -> void* {
        void* p = ws + off;
        off += (bytes + 255) & ~(size_t)255;
        return p;
    };
    unsigned* hb     = (unsigned*)alloc((size_t)M * 64 * 4);   // bf16 pairs
    float*    a_src  = (float*)   alloc((size_t)M * 2 * 4);
    float*    a_dst  = (float*)   alloc((size_t)M * 2 * 4);
    int*      count  = (int*)     alloc((size_t)M * 4);
    int*      incl   = (int*)     alloc((size_t)M * 4);
    int*      bsum   = (int*)     alloc((size_t)nb1 * 4);
    int*      rowptr = (int*)     alloc((size_t)(M + 1) * 4);
    int*      pos    = (int*)     alloc((size_t)E * 4);
    uint2*    payload= (uint2*)   alloc((size_t)E * 8);
    float*    V      = (float*)   alloc(32);

    hipMemsetAsync(count, 0, (size_t)M * 4, stream);

    k_fold_edge<<<1, 64, 0, stream>>>(We, attE, V);
    k_gemm_h<<<(M + 63) / 64, 256, 0, stream>>>(x, W, attS, attD, hb, a_src, a_dst, M);
    k_count<<<(E + 255) / 256, 256, 0, stream>>>(ei, count, pos, E);
    k_scan_a<<<nb1, 256, 0, stream>>>(count, incl, bsum, M);
    k_scan_b<<<1, 512, 0, stream>>>(bsum, nb1);
    k_scan_c<<<nb1, 256, 0, stream>>>(count, incl, bsum, rowptr, M);
    k_edge2<<<(E + 255) / 256, 256, 0, stream>>>(ei, ea, a_src, a_dst, V, rowptr, pos, payload, E);
    k_gather<<<(M + 3) / 4, 256, 0, stream>>>(payload, rowptr, hb, bias, gamma, beta,
                                              (float*)d_out, M);
}

// Round 3
// 223.095 us; speedup vs baseline: 2.6757x; 1.2797x over previous
//
#include <hip/hip_runtime.h>
#include <hip/hip_fp16.h>
#include <math.h>

#define IN_C 128
#define HC   128
#define OUT_C 64
#define NEG_SLOPE 0.2f
#define LN_EPS 1e-5f

// round-to-nearest-even bf16 pack of two floats -> uint (a=low, b=high)
__device__ inline unsigned bf16pack(float a, float b) {
    unsigned ua = __float_as_uint(a), ub = __float_as_uint(b);
    ua = (ua + 0x7fffu + ((ua >> 16) & 1u)) >> 16;
    ub = (ub + 0x7fffu + ((ub >> 16) & 1u)) >> 16;
    return ua | (ub << 16);
}

// ---------------------------------------------------------------------------
// K1 fused: blocks [0,GB) do the x@W GEMM with fused attention-logit +
// bf16-pack epilogue; blocks [GB,GB+CB) do the edge count pass (the only
// atomic pass); block GB+CB folds att_edge into W_edge (8 dots).
// The count work overlaps the VALU-dense GEMM instead of serializing.
// ---------------------------------------------------------------------------
__global__ __launch_bounds__(256) void k_fused1(
        const float* __restrict__ x, const float* __restrict__ W,
        const float* __restrict__ attS, const float* __restrict__ attD,
        unsigned* __restrict__ hb, float* __restrict__ a_src,
        float* __restrict__ a_dst, int M,
        const int* __restrict__ ei, int* __restrict__ count,
        int* __restrict__ pos, int E, int GB, int CB,
        const float* __restrict__ W_edge, const float* __restrict__ att_edge,
        float* __restrict__ V) {
    __shared__ float xT[128 * 68];
    const int bid = blockIdx.x;
    const int t = threadIdx.x;

    if (bid >= GB) {
        if (bid == GB + CB) {                 // fold att_edge into W_edge
            if (t < 8) {
                int d = t >> 1, h = t & 1;
                float s = 0.f;
                for (int c = 0; c < 64; ++c)
                    s += W_edge[d * HC + h * 64 + c] * att_edge[h * 64 + c];
                V[d * 2 + h] = s;
            }
            return;
        }
        int e = (bid - GB) * 256 + t;         // count pass
        if (e < E) pos[e] = atomicAdd(&count[ei[E + e]], 1);
        return;
    }

    // ---- GEMM branch ----
    const int brow = bid * 64;
    const float4* x4 = (const float4*)x;

    #pragma unroll
    for (int i = 0; i < 8; ++i) {
        int idx = i * 256 + t;
        int r = idx >> 5, cg = idx & 31;
        int row = brow + r;
        float4 v = make_float4(0.f, 0.f, 0.f, 0.f);
        if (row < M) v = x4[(size_t)row * 32 + cg];
        int k0 = cg * 4;
        xT[(k0 + 0) * 68 + r] = v.x;
        xT[(k0 + 1) * 68 + r] = v.y;
        xT[(k0 + 2) * 68 + r] = v.z;
        xT[(k0 + 3) * 68 + r] = v.w;
    }
    __syncthreads();

    const int tx = t & 31, ty = t >> 5;
    float acc[8][4];
    #pragma unroll
    for (int j = 0; j < 8; ++j)
        #pragma unroll
        for (int c = 0; c < 4; ++c) acc[j][c] = 0.f;

    const float4* W4 = (const float4*)W;
    #pragma unroll 4
    for (int k = 0; k < 128; ++k) {
        float4 w4 = W4[k * 32 + tx];
        float xr[8];
        #pragma unroll
        for (int j = 0; j < 8; ++j) xr[j] = xT[k * 68 + ty * 8 + j];
        #pragma unroll
        for (int j = 0; j < 8; ++j) {
            acc[j][0] += xr[j] * w4.x;
            acc[j][1] += xr[j] * w4.y;
            acc[j][2] += xr[j] * w4.z;
            acc[j][3] += xr[j] * w4.w;
        }
    }

    float as4[4], ad4[4];
    #pragma unroll
    for (int c = 0; c < 4; ++c) {
        as4[c] = attS[4 * tx + c];
        ad4[c] = attD[4 * tx + c];
    }

    #pragma unroll
    for (int j = 0; j < 8; ++j) {
        int row = brow + ty * 8 + j;
        float ps = 0.f, pd = 0.f;
        #pragma unroll
        for (int c = 0; c < 4; ++c) {
            ps += acc[j][c] * as4[c];
            pd += acc[j][c] * ad4[c];
        }
        #pragma unroll
        for (int m = 1; m < 16; m <<= 1) {
            ps += __shfl_xor(ps, m);
            pd += __shfl_xor(pd, m);
        }
        float p0 = __shfl_xor(acc[j][0], 16);
        float p1 = __shfl_xor(acc[j][1], 16);
        float p2 = __shfl_xor(acc[j][2], 16);
        float p3 = __shfl_xor(acc[j][3], 16);
        if (row < M) {
            if ((t & 15) == 0) {
                int head = (tx >> 4) & 1;
                a_src[2 * row + head] = ps;
                a_dst[2 * row + head] = pd;
            }
            if (tx < 16) {
                uint4 u;
                u.x = bf16pack(acc[j][0], p0);
                u.y = bf16pack(acc[j][1], p1);
                u.z = bf16pack(acc[j][2], p2);
                u.w = bf16pack(acc[j][3], p3);
                ((uint4*)hb)[(size_t)row * 16 + tx] = u;
            }
        }
    }
}

// ---------------------------------------------------------------------------
// K2a/b/c: exclusive scan of count[] -> rowptr[]
// ---------------------------------------------------------------------------
__global__ __launch_bounds__(256) void k_scan_a(const int* __restrict__ count,
                                                int* __restrict__ incl,
                                                int* __restrict__ bsum, int n) {
    __shared__ int sm[256];
    int t = threadIdx.x, i = blockIdx.x * 256 + t;
    int v = (i < n) ? count[i] : 0;
    sm[t] = v;
    __syncthreads();
    for (int off = 1; off < 256; off <<= 1) {
        int u = (t >= off) ? sm[t - off] : 0;
        __syncthreads();
        sm[t] += u;
        __syncthreads();
    }
    if (i < n) incl[i] = sm[t];
    if (t == 255) bsum[blockIdx.x] = sm[255];
}

__global__ __launch_bounds__(512) void k_scan_b(int* __restrict__ bsum, int nb) {
    __shared__ int sm[512];
    int t = threadIdx.x;
    int v = (t < nb) ? bsum[t] : 0;
    sm[t] = v;
    __syncthreads();
    for (int off = 1; off < 512; off <<= 1) {
        int u = (t >= off) ? sm[t - off] : 0;
        __syncthreads();
        sm[t] += u;
        __syncthreads();
    }
    if (t < nb) bsum[t] = sm[t] - v;
}

__global__ __launch_bounds__(256) void k_scan_c(const int* __restrict__ count,
                                                const int* __restrict__ incl,
                                                const int* __restrict__ bsum,
                                                int* __restrict__ rowptr, int n) {
    int i = blockIdx.x * 256 + threadIdx.x;
    if (i >= n) return;
    int r = bsum[blockIdx.x] + incl[i] - count[i];
    rowptr[i] = r;
    if (i == n - 1) rowptr[n] = bsum[blockIdx.x] + incl[i];
}

// ---------------------------------------------------------------------------
// K3: edge scatter — alpha/exp, write 8B payload {src, half2{e0,e1}} into
// CSR slot rowptr[d]+pos[e]. Zero atomics.
// ---------------------------------------------------------------------------
__global__ __launch_bounds__(256) void k_edge2(const int* __restrict__ ei,
                                               const float* __restrict__ ea,
                                               const float* __restrict__ a_src,
                                               const float* __restrict__ a_dst,
                                               const float* __restrict__ V,
                                               const int* __restrict__ rowptr,
                                               const int* __restrict__ pos,
                                               uint2* __restrict__ payload, int E) {
    int e = blockIdx.x * 256 + threadIdx.x;
    if (e >= E) return;
    int s = ei[e], d = ei[E + e];
    float4 a = ((const float4*)ea)[e];
    float ae0 = a.x * V[0] + a.y * V[2] + a.z * V[4] + a.w * V[6];
    float ae1 = a.x * V[1] + a.y * V[3] + a.z * V[5] + a.w * V[7];
    float2 as = ((const float2*)a_src)[s];
    float2 ad = ((const float2*)a_dst)[d];
    float al0 = as.x + ad.x + ae0; al0 = al0 > 0.f ? al0 : NEG_SLOPE * al0;
    float al1 = as.y + ad.y + ae1; al1 = al1 > 0.f ? al1 : NEG_SLOPE * al1;
    __half2 hx = __floats2half2_rn(__expf(al0), __expf(al1));
    int slot = rowptr[d] + pos[e];
    payload[slot] = make_uint2((unsigned)s, *reinterpret_cast<unsigned*>(&hx));
}

// ---------------------------------------------------------------------------
// K4: gather per node (wave per node, lane = channel).
// Lane-parallel payload load (one coalesced load covers <=64 neighbors),
// src/ex broadcast via shuffles -> hb loads are independent (deep MLP).
// Denominator via single wave-reduction. Fused head-mean+bias+LN+ReLU.
// ---------------------------------------------------------------------------
__global__ __launch_bounds__(256) void k_gather(const uint2* __restrict__ payload,
                                                const int* __restrict__ rowptr,
                                                const unsigned* __restrict__ hb,
                                                const float* __restrict__ bias,
                                                const float* __restrict__ gamma,
                                                const float* __restrict__ beta,
                                                float* __restrict__ out, int M) {
    int w = threadIdx.x >> 6, lane = threadIdx.x & 63;
    int n = blockIdx.x * 4 + w;
    if (n >= M) return;
    int beg = rowptr[n], end = rowptr[n + 1];
    float acc0 = 0.f, acc1 = 0.f, pe0 = 0.f, pe1 = 0.f;
    const unsigned* hbl = hb + lane;

    for (int base = beg; base < end; base += 64) {
        int cnt = end - base; if (cnt > 64) cnt = 64;
        uint2 p = make_uint2(0u, 0u);
        if (lane < cnt) p = payload[base + lane];
        {   // per-lane denominator contribution (0 for inactive lanes)
            __half2 he = *reinterpret_cast<__half2*>(&p.y);
            pe0 += __low2float(he);
            pe1 += __high2float(he);
        }
        int j = 0;
        for (; j + 4 <= cnt; j += 4) {
            unsigned s0 = __shfl(p.x, j + 0), s1 = __shfl(p.x, j + 1);
            unsigned s2 = __shfl(p.x, j + 2), s3 = __shfl(p.x, j + 3);
            unsigned w0 = __shfl(p.y, j + 0), w1 = __shfl(p.y, j + 1);
            unsigned w2 = __shfl(p.y, j + 2), w3 = __shfl(p.y, j + 3);
            unsigned h0 = hbl[(size_t)s0 * 64];
            unsigned h1 = hbl[(size_t)s1 * 64];
            unsigned h2 = hbl[(size_t)s2 * 64];
            unsigned h3 = hbl[(size_t)s3 * 64];
            __half2 q0 = *reinterpret_cast<__half2*>(&w0);
            __half2 q1 = *reinterpret_cast<__half2*>(&w1);
            __half2 q2 = *reinterpret_cast<__half2*>(&w2);
            __half2 q3 = *reinterpret_cast<__half2*>(&w3);
            acc0 += __low2float(q0)  * __uint_as_float(h0 << 16);
            acc1 += __high2float(q0) * __uint_as_float(h0 & 0xffff0000u);
            acc0 += __low2float(q1)  * __uint_as_float(h1 << 16);
            acc1 += __high2float(q1) * __uint_as_float(h1 & 0xffff0000u);
            acc0 += __low2float(q2)  * __uint_as_float(h2 << 16);
            acc1 += __high2float(q2) * __uint_as_float(h2 & 0xffff0000u);
            acc0 += __low2float(q3)  * __uint_as_float(h3 << 16);
            acc1 += __high2float(q3) * __uint_as_float(h3 & 0xffff0000u);
        }
        for (; j < cnt; ++j) {
            unsigned s0 = __shfl(p.x, j), w0 = __shfl(p.y, j);
            unsigned h0 = hbl[(size_t)s0 * 64];
            __half2 q0 = *reinterpret_cast<__half2*>(&w0);
            acc0 += __low2float(q0)  * __uint_as_float(h0 << 16);
            acc1 += __high2float(q0) * __uint_as_float(h0 & 0xffff0000u);
        }
    }

    float d0 = pe0, d1 = pe1;
    #pragma unroll
    for (int m = 32; m; m >>= 1) {
        d0 += __shfl_xor(d0, m);
        d1 += __shfl_xor(d1, m);
    }

    float o = 0.5f * (acc0 / (d0 + 1e-16f) + acc1 / (d1 + 1e-16f)) + bias[lane];
    float mu = o;
    #pragma unroll
    for (int m = 32; m; m >>= 1) mu += __shfl_xor(mu, m);
    mu *= (1.f / 64.f);
    float c = o - mu;
    float v = c * c;
    #pragma unroll
    for (int m = 32; m; m >>= 1) v += __shfl_xor(v, m);
    v *= (1.f / 64.f);
    float y = c * rsqrtf(v + LN_EPS) * gamma[lane] + beta[lane];
    out[(size_t)n * OUT_C + lane] = fmaxf(y, 0.f);
}

// ---------------------------------------------------------------------------
extern "C" void kernel_launch(void* const* d_in, const int* in_sizes, int n_in,
                              void* d_out, int out_size, void* d_ws, size_t ws_size,
                              hipStream_t stream) {
    const float* x     = (const float*)d_in[0];
    const int*   ei    = (const int*)d_in[1];
    const float* ea    = (const float*)d_in[2];
    const float* W     = (const float*)d_in[3];
    const float* attS  = (const float*)d_in[4];
    const float* attD  = (const float*)d_in[5];
    const float* We    = (const float*)d_in[6];
    const float* attE  = (const float*)d_in[7];
    const float* bias  = (const float*)d_in[8];
    const float* gamma = (const float*)d_in[9];
    const float* beta  = (const float*)d_in[10];

    const int M = in_sizes[0] / IN_C;      // 100000
    const int E = in_sizes[1] / 2;         // 1600000
    const int nb1 = (M + 255) / 256;       // 391 <= 512
    const int GB = (M + 63) / 64;          // gemm blocks
    const int CB = (E + 255) / 256;        // count blocks

    char* ws = (char*)d_ws;
    size_t off = 0;
    auto alloc = [&](size_t bytes) -> void* {
        void* p = ws + off;
        off += (bytes + 255) & ~(size_t)255;
        return p;
    };
    unsigned* hb     = (unsigned*)alloc((size_t)M * 64 * 4);
    float*    a_src  = (float*)   alloc((size_t)M * 2 * 4);
    float*    a_dst  = (float*)   alloc((size_t)M * 2 * 4);
    int*      count  = (int*)     alloc((size_t)M * 4);
    int*      incl   = (int*)     alloc((size_t)M * 4);
    int*      bsum   = (int*)     alloc((size_t)nb1 * 4);
    int*      rowptr = (int*)     alloc((size_t)(M + 1) * 4);
    int*      pos    = (int*)     alloc((size_t)E * 4);
    uint2*    payload= (uint2*)   alloc((size_t)E * 8);
    float*    V      = (float*)   alloc(32);

    hipMemsetAsync(count, 0, (size_t)M * 4, stream);

    k_fused1<<<GB + CB + 1, 256, 0, stream>>>(x, W, attS, attD, hb, a_src, a_dst, M,
                                              ei, count, pos, E, GB, CB, We, attE, V);
    k_scan_a<<<nb1, 256, 0, stream>>>(count, incl, bsum, M);
    k_scan_b<<<1, 512, 0, stream>>>(bsum, nb1);
    k_scan_c<<<nb1, 256, 0, stream>>>(count, incl, bsum, rowptr, M);
    k_edge2<<<(E + 255) / 256, 256, 0, stream>>>(ei, ea, a_src, a_dst, V, rowptr, pos, payload, E);
    k_gather<<<(M + 3) / 4, 256, 0, stream>>>(payload, rowptr, hb, bias, gamma, beta,
                                              (float*)d_out, M);
}

// Round 4
// 213.404 us; speedup vs baseline: 2.7972x; 1.0454x over previous
//
#include <hip/hip_runtime.h>
#include <hip/hip_fp16.h>
#include <math.h>

#define IN_C 128
#define HC   128
#define OUT_C 64
#define NEG_SLOPE 0.2f
#define LN_EPS 1e-5f

// round-to-nearest-even bf16 pack of two floats -> uint (a=low, b=high)
__device__ inline unsigned bf16pack(float a, float b) {
    unsigned ua = __float_as_uint(a), ub = __float_as_uint(b);
    ua = (ua + 0x7fffu + ((ua >> 16) & 1u)) >> 16;
    ub = (ub + 0x7fffu + ((ub >> 16) & 1u)) >> 16;
    return ua | (ub << 16);
}

// ---------------------------------------------------------------------------
// K1 fused, INTERLEAVED: grid = GB*5 blocks. Within each group of 5
// consecutive blocks: 4 count blocks + 1 GEMM block. This keeps a
// GEMM(VALU-bound) / count(atomic-latency-bound) mix resident on every CU
// for the whole kernel so the two pipes overlap (time ~ max, not sum).
//   r5==4 -> GEMM block g5 (x@W, fused attn-logit + bf16-pack epilogue)
//   r5<4  -> count block cid=bid-g5 (1 atomicAdd per edge, saves rank)
//   cid==CB spare block -> fold att_edge into W_edge (8 dots)
// ---------------------------------------------------------------------------
__global__ __launch_bounds__(256) void k_fused1(
        const float* __restrict__ x, const float* __restrict__ W,
        const float* __restrict__ attS, const float* __restrict__ attD,
        unsigned* __restrict__ hb, float* __restrict__ a_src,
        float* __restrict__ a_dst, int M,
        const int* __restrict__ ei, int* __restrict__ count,
        int* __restrict__ pos, int E, int GB, int CB,
        const float* __restrict__ W_edge, const float* __restrict__ att_edge,
        float* __restrict__ V) {
    __shared__ float xT[128 * 68];
    const int bid = blockIdx.x;
    const int t = threadIdx.x;
    const int r5 = bid % 5, g5 = bid / 5;

    if (r5 != 4) {
        const int cid = bid - g5;            // count-block index
        int e = cid * 256 + t;
        if (e < E) {
            pos[e] = atomicAdd(&count[ei[E + e]], 1);
        } else if (cid == CB && t < 8) {     // spare block: fold V
            int d = t >> 1, h = t & 1;
            float s = 0.f;
            for (int c = 0; c < 64; ++c)
                s += W_edge[d * HC + h * 64 + c] * att_edge[h * 64 + c];
            V[d * 2 + h] = s;
        }
        return;
    }

    // ---- GEMM branch (block g5 in [0,GB)) ----
    const int brow = g5 * 64;
    const float4* x4 = (const float4*)x;

    #pragma unroll
    for (int i = 0; i < 8; ++i) {
        int idx = i * 256 + t;
        int r = idx >> 5, cg = idx & 31;
        int row = brow + r;
        float4 v = make_float4(0.f, 0.f, 0.f, 0.f);
        if (row < M) v = x4[(size_t)row * 32 + cg];
        int k0 = cg * 4;
        xT[(k0 + 0) * 68 + r] = v.x;
        xT[(k0 + 1) * 68 + r] = v.y;
        xT[(k0 + 2) * 68 + r] = v.z;
        xT[(k0 + 3) * 68 + r] = v.w;
    }
    __syncthreads();

    const int tx = t & 31, ty = t >> 5;
    float acc[8][4];
    #pragma unroll
    for (int j = 0; j < 8; ++j)
        #pragma unroll
        for (int c = 0; c < 4; ++c) acc[j][c] = 0.f;

    const float4* W4 = (const float4*)W;
    #pragma unroll 4
    for (int k = 0; k < 128; ++k) {
        float4 w4 = W4[k * 32 + tx];
        float4 xa = *(const float4*)&xT[k * 68 + ty * 8];     // ds_read_b128
        float4 xb = *(const float4*)&xT[k * 68 + ty * 8 + 4]; // ds_read_b128
        float xr[8] = {xa.x, xa.y, xa.z, xa.w, xb.x, xb.y, xb.z, xb.w};
        #pragma unroll
        for (int j = 0; j < 8; ++j) {
            acc[j][0] += xr[j] * w4.x;
            acc[j][1] += xr[j] * w4.y;
            acc[j][2] += xr[j] * w4.z;
            acc[j][3] += xr[j] * w4.w;
        }
    }

    float as4[4], ad4[4];
    #pragma unroll
    for (int c = 0; c < 4; ++c) {
        as4[c] = attS[4 * tx + c];
        ad4[c] = attD[4 * tx + c];
    }

    #pragma unroll
    for (int j = 0; j < 8; ++j) {
        int row = brow + ty * 8 + j;
        float ps = 0.f, pd = 0.f;
        #pragma unroll
        for (int c = 0; c < 4; ++c) {
            ps += acc[j][c] * as4[c];
            pd += acc[j][c] * ad4[c];
        }
        #pragma unroll
        for (int m = 1; m < 16; m <<= 1) {
            ps += __shfl_xor(ps, m);
            pd += __shfl_xor(pd, m);
        }
        float p0 = __shfl_xor(acc[j][0], 16);
        float p1 = __shfl_xor(acc[j][1], 16);
        float p2 = __shfl_xor(acc[j][2], 16);
        float p3 = __shfl_xor(acc[j][3], 16);
        if (row < M) {
            if ((t & 15) == 0) {
                int head = (tx >> 4) & 1;
                a_src[2 * row + head] = ps;
                a_dst[2 * row + head] = pd;
            }
            if (tx < 16) {
                uint4 u;
                u.x = bf16pack(acc[j][0], p0);
                u.y = bf16pack(acc[j][1], p1);
                u.z = bf16pack(acc[j][2], p2);
                u.w = bf16pack(acc[j][3], p3);
                ((uint4*)hb)[(size_t)row * 16 + tx] = u;
            }
        }
    }
}

// ---------------------------------------------------------------------------
// K2a/b/c: exclusive scan of count[] -> rowptr[]
// ---------------------------------------------------------------------------
__global__ __launch_bounds__(256) void k_scan_a(const int* __restrict__ count,
                                                int* __restrict__ incl,
                                                int* __restrict__ bsum, int n) {
    __shared__ int sm[256];
    int t = threadIdx.x, i = blockIdx.x * 256 + t;
    int v = (i < n) ? count[i] : 0;
    sm[t] = v;
    __syncthreads();
    for (int off = 1; off < 256; off <<= 1) {
        int u = (t >= off) ? sm[t - off] : 0;
        __syncthreads();
        sm[t] += u;
        __syncthreads();
    }
    if (i < n) incl[i] = sm[t];
    if (t == 255) bsum[blockIdx.x] = sm[255];
}

__global__ __launch_bounds__(512) void k_scan_b(int* __restrict__ bsum, int nb) {
    __shared__ int sm[512];
    int t = threadIdx.x;
    int v = (t < nb) ? bsum[t] : 0;
    sm[t] = v;
    __syncthreads();
    for (int off = 1; off < 512; off <<= 1) {
        int u = (t >= off) ? sm[t - off] : 0;
        __syncthreads();
        sm[t] += u;
        __syncthreads();
    }
    if (t < nb) bsum[t] = sm[t] - v;
}

__global__ __launch_bounds__(256) void k_scan_c(const int* __restrict__ count,
                                                const int* __restrict__ incl,
                                                const int* __restrict__ bsum,
                                                int* __restrict__ rowptr, int n) {
    int i = blockIdx.x * 256 + threadIdx.x;
    if (i >= n) return;
    int r = bsum[blockIdx.x] + incl[i] - count[i];
    rowptr[i] = r;
    if (i == n - 1) rowptr[n] = bsum[blockIdx.x] + incl[i];
}

// ---------------------------------------------------------------------------
// K3: edge scatter — alpha/exp, write 8B payload {src, half2{e0,e1}} into
// CSR slot rowptr[d]+pos[e]. Zero atomics.
// ---------------------------------------------------------------------------
__global__ __launch_bounds__(256) void k_edge2(const int* __restrict__ ei,
                                               const float* __restrict__ ea,
                                               const float* __restrict__ a_src,
                                               const float* __restrict__ a_dst,
                                               const float* __restrict__ V,
                                               const int* __restrict__ rowptr,
                                               const int* __restrict__ pos,
                                               uint2* __restrict__ payload, int E) {
    int e = blockIdx.x * 256 + threadIdx.x;
    if (e >= E) return;
    int s = ei[e], d = ei[E + e];
    float4 a = ((const float4*)ea)[e];
    float ae0 = a.x * V[0] + a.y * V[2] + a.z * V[4] + a.w * V[6];
    float ae1 = a.x * V[1] + a.y * V[3] + a.z * V[5] + a.w * V[7];
    float2 as = ((const float2*)a_src)[s];
    float2 ad = ((const float2*)a_dst)[d];
    float al0 = as.x + ad.x + ae0; al0 = al0 > 0.f ? al0 : NEG_SLOPE * al0;
    float al1 = as.y + ad.y + ae1; al1 = al1 > 0.f ? al1 : NEG_SLOPE * al1;
    __half2 hx = __floats2half2_rn(__expf(al0), __expf(al1));
    int slot = rowptr[d] + pos[e];
    payload[slot] = make_uint2((unsigned)s, *reinterpret_cast<unsigned*>(&hx));
}

// ---------------------------------------------------------------------------
// K4: gather per node (wave per node, lane = channel).
// Lane-parallel payload load, src/ex broadcast via shuffles -> independent
// hb loads (deep MLP). Denominator via one wave-reduction. Fused
// head-mean + bias + LayerNorm + ReLU.
// ---------------------------------------------------------------------------
__global__ __launch_bounds__(256) void k_gather(const uint2* __restrict__ payload,
                                                const int* __restrict__ rowptr,
                                                const unsigned* __restrict__ hb,
                                                const float* __restrict__ bias,
                                                const float* __restrict__ gamma,
                                                const float* __restrict__ beta,
                                                float* __restrict__ out, int M) {
    int w = threadIdx.x >> 6, lane = threadIdx.x & 63;
    int n = blockIdx.x * 4 + w;
    if (n >= M) return;
    int beg = rowptr[n], end = rowptr[n + 1];
    float acc0 = 0.f, acc1 = 0.f, pe0 = 0.f, pe1 = 0.f;
    const unsigned* hbl = hb + lane;

    for (int base = beg; base < end; base += 64) {
        int cnt = end - base; if (cnt > 64) cnt = 64;
        uint2 p = make_uint2(0u, 0u);
        if (lane < cnt) p = payload[base + lane];
        {
            __half2 he = *reinterpret_cast<__half2*>(&p.y);
            pe0 += __low2float(he);
            pe1 += __high2float(he);
        }
        int j = 0;
        for (; j + 4 <= cnt; j += 4) {
            unsigned s0 = __shfl(p.x, j + 0), s1 = __shfl(p.x, j + 1);
            unsigned s2 = __shfl(p.x, j + 2), s3 = __shfl(p.x, j + 3);
            unsigned w0 = __shfl(p.y, j + 0), w1 = __shfl(p.y, j + 1);
            unsigned w2 = __shfl(p.y, j + 2), w3 = __shfl(p.y, j + 3);
            unsigned h0 = hbl[(size_t)s0 * 64];
            unsigned h1 = hbl[(size_t)s1 * 64];
            unsigned h2 = hbl[(size_t)s2 * 64];
            unsigned h3 = hbl[(size_t)s3 * 64];
            __half2 q0 = *reinterpret_cast<__half2*>(&w0);
            __half2 q1 = *reinterpret_cast<__half2*>(&w1);
            __half2 q2 = *reinterpret_cast<__half2*>(&w2);
            __half2 q3 = *reinterpret_cast<__half2*>(&w3);
            acc0 += __low2float(q0)  * __uint_as_float(h0 << 16);
            acc1 += __high2float(q0) * __uint_as_float(h0 & 0xffff0000u);
            acc0 += __low2float(q1)  * __uint_as_float(h1 << 16);
            acc1 += __high2float(q1) * __uint_as_float(h1 & 0xffff0000u);
            acc0 += __low2float(q2)  * __uint_as_float(h2 << 16);
            acc1 += __high2float(q2) * __uint_as_float(h2 & 0xffff0000u);
            acc0 += __low2float(q3)  * __uint_as_float(h3 << 16);
            acc1 += __high2float(q3) * __uint_as_float(h3 & 0xffff0000u);
        }
        for (; j < cnt; ++j) {
            unsigned s0 = __shfl(p.x, j), w0 = __shfl(p.y, j);
            unsigned h0 = hbl[(size_t)s0 * 64];
            __half2 q0 = *reinterpret_cast<__half2*>(&w0);
            acc0 += __low2float(q0)  * __uint_as_float(h0 << 16);
            acc1 += __high2float(q0) * __uint_as_float(h0 & 0xffff0000u);
        }
    }

    float d0 = pe0, d1 = pe1;
    #pragma unroll
    for (int m = 32; m; m >>= 1) {
        d0 += __shfl_xor(d0, m);
        d1 += __shfl_xor(d1, m);
    }

    float o = 0.5f * (acc0 / (d0 + 1e-16f) + acc1 / (d1 + 1e-16f)) + bias[lane];
    float mu = o;
    #pragma unroll
    for (int m = 32; m; m >>= 1) mu += __shfl_xor(mu, m);
    mu *= (1.f / 64.f);
    float c = o - mu;
    float v = c * c;
    #pragma unroll
    for (int m = 32; m; m >>= 1) v += __shfl_xor(v, m);
    v *= (1.f / 64.f);
    float y = c * rsqrtf(v + LN_EPS) * gamma[lane] + beta[lane];
    out[(size_t)n * OUT_C + lane] = fmaxf(y, 0.f);
}

// ---------------------------------------------------------------------------
extern "C" void kernel_launch(void* const* d_in, const int* in_sizes, int n_in,
                              void* d_out, int out_size, void* d_ws, size_t ws_size,
                              hipStream_t stream) {
    const float* x     = (const float*)d_in[0];
    const int*   ei    = (const int*)d_in[1];
    const float* ea    = (const float*)d_in[2];
    const float* W     = (const float*)d_in[3];
    const float* attS  = (const float*)d_in[4];
    const float* attD  = (const float*)d_in[5];
    const float* We    = (const float*)d_in[6];
    const float* attE  = (const float*)d_in[7];
    const float* bias  = (const float*)d_in[8];
    const float* gamma = (const float*)d_in[9];
    const float* beta  = (const float*)d_in[10];

    const int M = in_sizes[0] / IN_C;      // 100000
    const int E = in_sizes[1] / 2;         // 1600000
    const int nb1 = (M + 255) / 256;       // 391 <= 512
    const int GB = (M + 63) / 64;          // 1563 gemm blocks
    const int CB = (E + 255) / 256;        // 6250 count blocks

    char* ws = (char*)d_ws;
    size_t off = 0;
    auto alloc = [&](size_t bytes) -> void* {
        void* p = ws + off;
        off += (bytes + 255) & ~(size_t)255;
        return p;
    };
    unsigned* hb     = (unsigned*)alloc((size_t)M * 64 * 4);
    float*    a_src  = (float*)   alloc((size_t)M * 2 * 4);
    float*    a_dst  = (float*)   alloc((size_t)M * 2 * 4);
    int*      count  = (int*)     alloc((size_t)M * 4);
    int*      incl   = (int*)     alloc((size_t)M * 4);
    int*      bsum   = (int*)     alloc((size_t)nb1 * 4);
    int*      rowptr = (int*)     alloc((size_t)(M + 1) * 4);
    int*      pos    = (int*)     alloc((size_t)E * 4);
    uint2*    payload= (uint2*)   alloc((size_t)E * 8);
    float*    V      = (float*)   alloc(32);

    hipMemsetAsync(count, 0, (size_t)M * 4, stream);

    // grid = GB*5: per 5 blocks -> 4 count + 1 gemm, interleaved so every CU
    // hosts both kinds throughout (GEMM VALU hides under atomic latency).
    k_fused1<<<GB * 5, 256, 0, stream>>>(x, W, attS, attD, hb, a_src, a_dst, M,
                                         ei, count, pos, E, GB, CB, We, attE, V);
    k_scan_a<<<nb1, 256, 0, stream>>>(count, incl, bsum, M);
    k_scan_b<<<1, 512, 0, stream>>>(bsum, nb1);
    k_scan_c<<<nb1, 256, 0, stream>>>(count, incl, bsum, rowptr, M);
    k_edge2<<<(E + 255) / 256, 256, 0, stream>>>(ei, ea, a_src, a_dst, V, rowptr, pos, payload, E);
    k_gather<<<(M + 3) / 4, 256, 0, stream>>>(payload, rowptr, hb, bias, gamma, beta,
                                              (float*)d_out, M);
}

// Round 5
// 194.982 us; speedup vs baseline: 3.0615x; 1.0945x over previous
//
#include <hip/hip_runtime.h>
#include <hip/hip_fp16.h>
#include <math.h>

#define IN_C 128
#define HC   128
#define OUT_C 64
#define NEG_SLOPE 0.2f
#define LN_EPS 1e-5f
#define CHUNK 4096        // edges per partition block
#define NBMAX 1024        // max buckets (dst>>7; M<=131072)

// round-to-nearest-even bf16 pack of two floats -> uint (a=low, b=high)
__device__ inline unsigned bf16pack(float a, float b) {
    unsigned ua = __float_as_uint(a), ub = __float_as_uint(b);
    ua = (ua + 0x7fffu + ((ua >> 16) & 1u)) >> 16;
    ub = (ub + 0x7fffu + ((ub >> 16) & 1u)) >> 16;
    return ua | (ub << 16);
}

// ---------------------------------------------------------------------------
// fold att_edge into W_edge:  V[d][h] = sum_c W_edge[d,h*64+c]*att_edge[h,c]
// ---------------------------------------------------------------------------
__global__ void k_fold_edge(const float* __restrict__ W_edge,
                            const float* __restrict__ att_edge,
                            float* __restrict__ V) {
    int t = threadIdx.x;
    if (t < 8) {
        int d = t >> 1, h = t & 1;
        float s = 0.f;
        for (int c = 0; c < 64; ++c)
            s += W_edge[d * HC + h * 64 + c] * att_edge[h * 64 + c];
        V[d * 2 + h] = s;
    }
}

// ---------------------------------------------------------------------------
// GEMM: h = x@W with fused attn-logit + bf16-pack epilogue (own kernel again)
// ---------------------------------------------------------------------------
__global__ __launch_bounds__(256) void k_gemm(const float* __restrict__ x,
                                              const float* __restrict__ W,
                                              const float* __restrict__ attS,
                                              const float* __restrict__ attD,
                                              unsigned* __restrict__ hb,
                                              float* __restrict__ a_src,
                                              float* __restrict__ a_dst, int M) {
    __shared__ float xT[128 * 68];
    const int t = threadIdx.x;
    const int brow = blockIdx.x * 64;
    const float4* x4 = (const float4*)x;

    #pragma unroll
    for (int i = 0; i < 8; ++i) {
        int idx = i * 256 + t;
        int r = idx >> 5, cg = idx & 31;
        int row = brow + r;
        float4 v = make_float4(0.f, 0.f, 0.f, 0.f);
        if (row < M) v = x4[(size_t)row * 32 + cg];
        int k0 = cg * 4;
        xT[(k0 + 0) * 68 + r] = v.x;
        xT[(k0 + 1) * 68 + r] = v.y;
        xT[(k0 + 2) * 68 + r] = v.z;
        xT[(k0 + 3) * 68 + r] = v.w;
    }
    __syncthreads();

    const int tx = t & 31, ty = t >> 5;
    float acc[8][4];
    #pragma unroll
    for (int j = 0; j < 8; ++j)
        #pragma unroll
        for (int c = 0; c < 4; ++c) acc[j][c] = 0.f;

    const float4* W4 = (const float4*)W;
    #pragma unroll 4
    for (int k = 0; k < 128; ++k) {
        float4 w4 = W4[k * 32 + tx];
        float4 xa = *(const float4*)&xT[k * 68 + ty * 8];
        float4 xb = *(const float4*)&xT[k * 68 + ty * 8 + 4];
        float xr[8] = {xa.x, xa.y, xa.z, xa.w, xb.x, xb.y, xb.z, xb.w};
        #pragma unroll
        for (int j = 0; j < 8; ++j) {
            acc[j][0] += xr[j] * w4.x;
            acc[j][1] += xr[j] * w4.y;
            acc[j][2] += xr[j] * w4.z;
            acc[j][3] += xr[j] * w4.w;
        }
    }

    float as4[4], ad4[4];
    #pragma unroll
    for (int c = 0; c < 4; ++c) {
        as4[c] = attS[4 * tx + c];
        ad4[c] = attD[4 * tx + c];
    }

    #pragma unroll
    for (int j = 0; j < 8; ++j) {
        int row = brow + ty * 8 + j;
        float ps = 0.f, pd = 0.f;
        #pragma unroll
        for (int c = 0; c < 4; ++c) {
            ps += acc[j][c] * as4[c];
            pd += acc[j][c] * ad4[c];
        }
        #pragma unroll
        for (int m = 1; m < 16; m <<= 1) {
            ps += __shfl_xor(ps, m);
            pd += __shfl_xor(pd, m);
        }
        float p0 = __shfl_xor(acc[j][0], 16);
        float p1 = __shfl_xor(acc[j][1], 16);
        float p2 = __shfl_xor(acc[j][2], 16);
        float p3 = __shfl_xor(acc[j][3], 16);
        if (row < M) {
            if ((t & 15) == 0) {
                int head = (tx >> 4) & 1;
                a_src[2 * row + head] = ps;
                a_dst[2 * row + head] = pd;
            }
            if (tx < 16) {
                uint4 u;
                u.x = bf16pack(acc[j][0], p0);
                u.y = bf16pack(acc[j][1], p1);
                u.z = bf16pack(acc[j][2], p2);
                u.w = bf16pack(acc[j][3], p3);
                ((uint4*)hb)[(size_t)row * 16 + tx] = u;
            }
        }
    }
}

// ---------------------------------------------------------------------------
// A1: per-chunk LDS histogram over NB buckets -> off[bucket][chunk] (counts)
// ---------------------------------------------------------------------------
__global__ __launch_bounds__(256) void k_hist(const int* __restrict__ ei_dst,
                                              int* __restrict__ off,
                                              int E, int NB, int PB) {
    __shared__ int hist[NBMAX];
    int pb = blockIdx.x, t = threadIdx.x;
    for (int i = t; i < NB; i += 256) hist[i] = 0;
    __syncthreads();
    int base = pb * CHUNK;
    int lim = E - base; if (lim > CHUNK) lim = CHUNK;
    for (int i = t; i < lim; i += 256)
        atomicAdd(&hist[ei_dst[base + i] >> 7], 1);
    __syncthreads();
    for (int i = t; i < NB; i += 256)
        off[(size_t)i * PB + pb] = hist[i];
}

// ---------------------------------------------------------------------------
// scan of off[] (n = NB*PB, bucket-major): 1024 elems/block, 3-kernel scan
// ---------------------------------------------------------------------------
__global__ __launch_bounds__(256) void k_scan1(int* __restrict__ a,
                                               int* __restrict__ bsum, int n) {
    __shared__ int sm[256];
    int t = threadIdx.x;
    int base = blockIdx.x * 1024 + t * 4;
    int v0 = 0, v1 = 0, v2 = 0, v3 = 0;
    if (base + 0 < n) v0 = a[base + 0];
    if (base + 1 < n) v1 = a[base + 1];
    if (base + 2 < n) v2 = a[base + 2];
    if (base + 3 < n) v3 = a[base + 3];
    int s = v0 + v1 + v2 + v3;
    sm[t] = s;
    __syncthreads();
    for (int o = 1; o < 256; o <<= 1) {
        int u = (t >= o) ? sm[t - o] : 0;
        __syncthreads();
        sm[t] += u;
        __syncthreads();
    }
    int excl = sm[t] - s;
    if (base + 0 < n) a[base + 0] = excl;
    if (base + 1 < n) a[base + 1] = excl + v0;
    if (base + 2 < n) a[base + 2] = excl + v0 + v1;
    if (base + 3 < n) a[base + 3] = excl + v0 + v1 + v2;
    if (t == 255) bsum[blockIdx.x] = sm[255];
}

__global__ __launch_bounds__(512) void k_scan2(int* __restrict__ bsum, int nb) {
    __shared__ int sm[512];
    int t = threadIdx.x;
    int v = (t < nb) ? bsum[t] : 0;
    sm[t] = v;
    __syncthreads();
    for (int o = 1; o < 512; o <<= 1) {
        int u = (t >= o) ? sm[t - o] : 0;
        __syncthreads();
        sm[t] += u;
        __syncthreads();
    }
    if (t < nb) bsum[t] = sm[t] - v;
}

__global__ __launch_bounds__(256) void k_scan3(int* __restrict__ a,
                                               const int* __restrict__ bsum, int n) {
    int add = bsum[blockIdx.x];
    int base = blockIdx.x * 1024 + threadIdx.x * 4;
    #pragma unroll
    for (int k = 0; k < 4; ++k)
        if (base + k < n) a[base + k] += add;
}

// ---------------------------------------------------------------------------
// A3: partition scatter. slot = scanned off[bucket][chunk] + LDS rank.
// payloadA = {src | dst_local<<17, half2(ae0,ae1)}  (ae = ea . V)
// ---------------------------------------------------------------------------
__global__ __launch_bounds__(256) void k_part(const int* __restrict__ ei,
                                              const float* __restrict__ ea,
                                              const float* __restrict__ V,
                                              const int* __restrict__ off,
                                              uint2* __restrict__ pA,
                                              int E, int NB, int PB) {
    __shared__ int cur[NBMAX];
    int pb = blockIdx.x, t = threadIdx.x;
    for (int i = t; i < NB; i += 256) cur[i] = off[(size_t)i * PB + pb];
    __syncthreads();
    float v0 = V[0], v1 = V[1], v2 = V[2], v3 = V[3];
    float v4 = V[4], v5 = V[5], v6 = V[6], v7 = V[7];
    int base = pb * CHUNK;
    int lim = E - base; if (lim > CHUNK) lim = CHUNK;
    for (int i = t; i < lim; i += 256) {
        int e = base + i;
        int s = ei[e], d = ei[E + e];
        float4 a = ((const float4*)ea)[e];
        float ae0 = a.x * v0 + a.y * v2 + a.z * v4 + a.w * v6;
        float ae1 = a.x * v1 + a.y * v3 + a.z * v5 + a.w * v7;
        int slot = atomicAdd(&cur[d >> 7], 1);
        __half2 h = __floats2half2_rn(ae0, ae1);
        pA[slot] = make_uint2((unsigned)s | ((unsigned)(d & 127) << 17),
                              *reinterpret_cast<unsigned*>(&h));
    }
}

// ---------------------------------------------------------------------------
// B: per-bucket CSR build + alpha/exp. One block per bucket (128 nodes).
// LDS count -> LDS scan -> rowptr; then alpha = a_src[src]+a_dst[dst]+ae,
// leaky-relu, exp, place {src, half2 ex} at CSR slot via LDS rank.
// ---------------------------------------------------------------------------
__global__ __launch_bounds__(256) void k_csr(const uint2* __restrict__ pA,
                                             const int* __restrict__ off,
                                             const float* __restrict__ a_src,
                                             const float* __restrict__ a_dst,
                                             int* __restrict__ rowptr,
                                             uint2* __restrict__ payload,
                                             int M, int E, int NB, int PB) {
    __shared__ int cnt[128];
    __shared__ int sc[128];
    __shared__ int cur[128];
    __shared__ float2 adl[128];
    int b = blockIdx.x, t = threadIdx.x;
    int n0 = b << 7;
    int nloc = M - n0; if (nloc > 128) nloc = 128;
    int s0 = off[(size_t)b * PB];
    int s1 = (b + 1 < NB) ? off[(size_t)(b + 1) * PB] : E;
    if (t < 128) {
        cnt[t] = 0;
        if (t < nloc) adl[t] = ((const float2*)a_dst)[n0 + t];
    }
    __syncthreads();
    for (int i = s0 + t; i < s1; i += 256)
        atomicAdd(&cnt[(pA[i].x >> 17) & 127], 1);
    __syncthreads();
    if (t < 128) sc[t] = cnt[t];
    __syncthreads();
    for (int o = 1; o < 128; o <<= 1) {
        int u = 0;
        if (t < 128 && t >= o) u = sc[t - o];
        __syncthreads();
        if (t < 128) sc[t] += u;
        __syncthreads();
    }
    if (t < 128) {
        int base = s0 + sc[t] - cnt[t];   // exclusive
        cur[t] = base;
        if (t < nloc) rowptr[n0 + t] = base;
    }
    if (b == NB - 1 && t == 0) rowptr[M] = E;
    __syncthreads();
    for (int i = s0 + t; i < s1; i += 256) {
        uint2 p = pA[i];
        int src = p.x & 0x1FFFF;
        int dl = (p.x >> 17) & 127;
        __half2 aeh = *reinterpret_cast<__half2*>(&p.y);
        float ae0 = __low2float(aeh), ae1 = __high2float(aeh);
        float2 as = ((const float2*)a_src)[src];
        float2 ad = adl[dl];
        float al0 = as.x + ad.x + ae0; al0 = al0 > 0.f ? al0 : NEG_SLOPE * al0;
        float al1 = as.y + ad.y + ae1; al1 = al1 > 0.f ? al1 : NEG_SLOPE * al1;
        __half2 hx = __floats2half2_rn(__expf(al0), __expf(al1));
        int pos = atomicAdd(&cur[dl], 1);
        payload[pos] = make_uint2((unsigned)src, *reinterpret_cast<unsigned*>(&hx));
    }
}

// ---------------------------------------------------------------------------
// gather per node (wave per node, lane = channel); lane-parallel payload
// load + shuffle broadcast; in-loop denominator; fused mean+bias+LN+ReLU.
// ---------------------------------------------------------------------------
__global__ __launch_bounds__(256) void k_gather(const uint2* __restrict__ payload,
                                                const int* __restrict__ rowptr,
                                                const unsigned* __restrict__ hb,
                                                const float* __restrict__ bias,
                                                const float* __restrict__ gamma,
                                                const float* __restrict__ beta,
                                                float* __restrict__ out, int M) {
    int w = threadIdx.x >> 6, lane = threadIdx.x & 63;
    int n = blockIdx.x * 4 + w;
    if (n >= M) return;
    int beg = rowptr[n], end = rowptr[n + 1];
    float acc0 = 0.f, acc1 = 0.f, pe0 = 0.f, pe1 = 0.f;
    const unsigned* hbl = hb + lane;

    for (int base = beg; base < end; base += 64) {
        int cnt = end - base; if (cnt > 64) cnt = 64;
        uint2 p = make_uint2(0u, 0u);
        if (lane < cnt) p = payload[base + lane];
        {
            __half2 he = *reinterpret_cast<__half2*>(&p.y);
            pe0 += __low2float(he);
            pe1 += __high2float(he);
        }
        int j = 0;
        for (; j + 4 <= cnt; j += 4) {
            unsigned s0 = __shfl(p.x, j + 0), s1 = __shfl(p.x, j + 1);
            unsigned s2 = __shfl(p.x, j + 2), s3 = __shfl(p.x, j + 3);
            unsigned w0 = __shfl(p.y, j + 0), w1 = __shfl(p.y, j + 1);
            unsigned w2 = __shfl(p.y, j + 2), w3 = __shfl(p.y, j + 3);
            unsigned h0 = hbl[(size_t)s0 * 64];
            unsigned h1 = hbl[(size_t)s1 * 64];
            unsigned h2 = hbl[(size_t)s2 * 64];
            unsigned h3 = hbl[(size_t)s3 * 64];
            __half2 q0 = *reinterpret_cast<__half2*>(&w0);
            __half2 q1 = *reinterpret_cast<__half2*>(&w1);
            __half2 q2 = *reinterpret_cast<__half2*>(&w2);
            __half2 q3 = *reinterpret_cast<__half2*>(&w3);
            acc0 += __low2float(q0)  * __uint_as_float(h0 << 16);
            acc1 += __high2float(q0) * __uint_as_float(h0 & 0xffff0000u);
            acc0 += __low2float(q1)  * __uint_as_float(h1 << 16);
            acc1 += __high2float(q1) * __uint_as_float(h1 & 0xffff0000u);
            acc0 += __low2float(q2)  * __uint_as_float(h2 << 16);
            acc1 += __high2float(q2) * __uint_as_float(h2 & 0xffff0000u);
            acc0 += __low2float(q3)  * __uint_as_float(h3 << 16);
            acc1 += __high2float(q3) * __uint_as_float(h3 & 0xffff0000u);
        }
        for (; j < cnt; ++j) {
            unsigned s0 = __shfl(p.x, j), w0 = __shfl(p.y, j);
            unsigned h0 = hbl[(size_t)s0 * 64];
            __half2 q0 = *reinterpret_cast<__half2*>(&w0);
            acc0 += __low2float(q0)  * __uint_as_float(h0 << 16);
            acc1 += __high2float(q0) * __uint_as_float(h0 & 0xffff0000u);
        }
    }

    float d0 = pe0, d1 = pe1;
    #pragma unroll
    for (int m = 32; m; m >>= 1) {
        d0 += __shfl_xor(d0, m);
        d1 += __shfl_xor(d1, m);
    }

    float o = 0.5f * (acc0 / (d0 + 1e-16f) + acc1 / (d1 + 1e-16f)) + bias[lane];
    float mu = o;
    #pragma unroll
    for (int m = 32; m; m >>= 1) mu += __shfl_xor(mu, m);
    mu *= (1.f / 64.f);
    float c = o - mu;
    float v = c * c;
    #pragma unroll
    for (int m = 32; m; m >>= 1) v += __shfl_xor(v, m);
    v *= (1.f / 64.f);
    float y = c * rsqrtf(v + LN_EPS) * gamma[lane] + beta[lane];
    out[(size_t)n * OUT_C + lane] = fmaxf(y, 0.f);
}

// ---------------------------------------------------------------------------
extern "C" void kernel_launch(void* const* d_in, const int* in_sizes, int n_in,
                              void* d_out, int out_size, void* d_ws, size_t ws_size,
                              hipStream_t stream) {
    const float* x     = (const float*)d_in[0];
    const int*   ei    = (const int*)d_in[1];
    const float* ea    = (const float*)d_in[2];
    const float* W     = (const float*)d_in[3];
    const float* attS  = (const float*)d_in[4];
    const float* attD  = (const float*)d_in[5];
    const float* We    = (const float*)d_in[6];
    const float* attE  = (const float*)d_in[7];
    const float* bias  = (const float*)d_in[8];
    const float* gamma = (const float*)d_in[9];
    const float* beta  = (const float*)d_in[10];

    const int M  = in_sizes[0] / IN_C;        // 100000
    const int E  = in_sizes[1] / 2;           // 1600000
    const int NB = (M + 127) >> 7;            // 782 buckets
    const int PB = (E + CHUNK - 1) / CHUNK;   // 391 partition chunks
    const int nS = NB * PB;                   // 305762 offsets
    const int nb2 = (nS + 1023) / 1024;       // 299 scan blocks (<=512)
    const int GB = (M + 63) / 64;             // 1563 gemm blocks

    char* ws = (char*)d_ws;
    size_t woff = 0;
    auto alloc = [&](size_t bytes) -> void* {
        void* p = ws + woff;
        woff += (bytes + 255) & ~(size_t)255;
        return p;
    };
    unsigned* hb     = (unsigned*)alloc((size_t)M * 64 * 4);
    float*    a_src  = (float*)   alloc((size_t)M * 2 * 4);
    float*    a_dst  = (float*)   alloc((size_t)M * 2 * 4);
    int*      off    = (int*)     alloc((size_t)nS * 4);
    int*      bsum   = (int*)     alloc((size_t)nb2 * 4);
    int*      rowptr = (int*)     alloc((size_t)(M + 1) * 4);
    uint2*    pA     = (uint2*)   alloc((size_t)E * 8);
    uint2*    payload= (uint2*)   alloc((size_t)E * 8);
    float*    V      = (float*)   alloc(32);

    k_fold_edge<<<1, 64, 0, stream>>>(We, attE, V);
    k_hist<<<PB, 256, 0, stream>>>(ei + E, off, E, NB, PB);
    k_gemm<<<GB, 256, 0, stream>>>(x, W, attS, attD, hb, a_src, a_dst, M);
    k_scan1<<<nb2, 256, 0, stream>>>(off, bsum, nS);
    k_scan2<<<1, 512, 0, stream>>>(bsum, nb2);
    k_scan3<<<nb2, 256, 0, stream>>>(off, bsum, nS);
    k_part<<<PB, 256, 0, stream>>>(ei, ea, V, off, pA, E, NB, PB);
    k_csr<<<NB, 256, 0, stream>>>(pA, off, a_src, a_dst, rowptr, payload, M, E, NB, PB);
    k_gather<<<(M + 3) / 4, 256, 0, stream>>>(payload, rowptr, hb, bias, gamma, beta,
                                              (float*)d_out, M);
}

// Round 6
// 172.041 us; speedup vs baseline: 3.4697x; 1.1333x over previous
//
#include <hip/hip_runtime.h>
#include <hip/hip_fp16.h>
#include <math.h>

#define IN_C 128
#define HC   128
#define OUT_C 64
#define NEG_SLOPE 0.2f
#define LN_EPS 1e-5f
#define CHUNK 4096        // edges per partition block
#define NBMAX 1024        // max buckets (dst>>7; M<=131072)

typedef __attribute__((ext_vector_type(8))) short bf16x8;
typedef __attribute__((ext_vector_type(4))) float f32x4;

// round-to-nearest-even bf16 pack of two floats -> uint (a=low, b=high)
__device__ inline unsigned bf16pack(float a, float b) {
    unsigned ua = __float_as_uint(a), ub = __float_as_uint(b);
    ua = (ua + 0x7fffu + ((ua >> 16) & 1u)) >> 16;
    ub = (ub + 0x7fffu + ((ub >> 16) & 1u)) >> 16;
    return ua | (ub << 16);
}

// ---------------------------------------------------------------------------
// prep: blocks 0..7 build WbfT[col][k] = bf16(W[k][col]) (32 KB, L1-resident
// for the GEMM); block 8 folds att_edge into W_edge (V[d][h], 8 dots).
// ---------------------------------------------------------------------------
__global__ __launch_bounds__(256) void k_prep(const float* __restrict__ W,
                                              const float* __restrict__ W_edge,
                                              const float* __restrict__ att_edge,
                                              unsigned short* __restrict__ WbfT,
                                              float* __restrict__ V) {
    int b = blockIdx.x, t = threadIdx.x;
    if (b < 8) {
        #pragma unroll
        for (int i = 0; i < 8; ++i) {
            int idx = b * 2048 + i * 256 + t;      // 0..16383
            int k = idx >> 7, col = idx & 127;
            unsigned u = __float_as_uint(W[idx]);
            WbfT[col * 128 + k] =
                (unsigned short)((u + 0x7fffu + ((u >> 16) & 1u)) >> 16);
        }
    } else if (t < 8) {
        int d = t >> 1, h = t & 1;
        float s = 0.f;
        for (int c = 0; c < 64; ++c)
            s += W_edge[d * HC + h * 64 + c] * att_edge[h * 64 + c];
        V[d * 2 + h] = s;
    }
}

// ---------------------------------------------------------------------------
// GEMM via MFMA (bf16): block = 64 rows, 4 waves x 16 rows. x staged bf16 in
// LDS with XOR swizzle (byte ^= (row&7)<<4) -> conflict-free b128 frag reads.
// B fragments read directly from WbfT (L1-hot). Epilogue: attn logits via
// 16-lane shuffle reduce + bf16 pair pack, from MFMA acc layout
// (col=lane&15, row=(lane>>4)*4+reg).
// ---------------------------------------------------------------------------
__global__ __launch_bounds__(256) void k_gemm(const float* __restrict__ x,
                                              const unsigned short* __restrict__ WbfT,
                                              const float* __restrict__ attS,
                                              const float* __restrict__ attD,
                                              unsigned* __restrict__ hb,
                                              float* __restrict__ a_src,
                                              float* __restrict__ a_dst, int M) {
    __shared__ unsigned xb[64 * 64];          // 64 rows x 128 bf16 = 16 KB
    const int t = threadIdx.x;
    const int brow = blockIdx.x * 64;
    const float4* x4 = (const float4*)x;

    #pragma unroll
    for (int i = 0; i < 8; ++i) {
        int idx = i * 256 + t;
        int row = idx >> 5, c4 = idx & 31;
        float4 v = make_float4(0.f, 0.f, 0.f, 0.f);
        if (brow + row < M) v = x4[(size_t)(brow + row) * 32 + c4];
        unsigned lo = bf16pack(v.x, v.y), hi = bf16pack(v.z, v.w);
        int byte = row * 256 + ((c4 * 8) ^ ((row & 7) << 4));
        *(uint2*)((char*)xb + byte) = make_uint2(lo, hi);
    }
    __syncthreads();

    const int w = t >> 6, lane = t & 63;
    const int col = lane & 15, qr = lane >> 4;
    f32x4 acc[8];
    #pragma unroll
    for (int ct = 0; ct < 8; ++ct) acc[ct] = (f32x4){0.f, 0.f, 0.f, 0.f};

    const int arow = w * 16 + col;            // A row within tile
    #pragma unroll
    for (int ks = 0; ks < 4; ++ks) {
        int abyte = arow * 256 + ((ks * 64 + qr * 16) ^ ((arow & 7) << 4));
        bf16x8 af = *(const bf16x8*)((const char*)xb + abyte);
        #pragma unroll
        for (int ct = 0; ct < 8; ++ct) {
            bf16x8 bfr = *(const bf16x8*)&WbfT[(size_t)(ct * 16 + col) * 128 + ks * 32 + qr * 8];
            acc[ct] = __builtin_amdgcn_mfma_f32_16x16x32_bf16(af, bfr, acc[ct], 0, 0, 0);
        }
    }

    // ---- epilogue: logits + bf16 pack ----
    float pS0[4], pS1[4], pD0[4], pD1[4];
    #pragma unroll
    for (int r = 0; r < 4; ++r) { pS0[r] = pS1[r] = pD0[r] = pD1[r] = 0.f; }
    #pragma unroll
    for (int ct = 0; ct < 8; ++ct) {
        float s = attS[ct * 16 + col], d = attD[ct * 16 + col];
        #pragma unroll
        for (int r = 0; r < 4; ++r) {
            float a = acc[ct][r];
            if (ct < 4) { pS0[r] += a * s; pD0[r] += a * d; }
            else        { pS1[r] += a * s; pD1[r] += a * d; }
        }
    }
    #pragma unroll
    for (int m = 1; m < 16; m <<= 1) {
        #pragma unroll
        for (int r = 0; r < 4; ++r) {
            pS0[r] += __shfl_xor(pS0[r], m);
            pS1[r] += __shfl_xor(pS1[r], m);
            pD0[r] += __shfl_xor(pD0[r], m);
            pD1[r] += __shfl_xor(pD1[r], m);
        }
    }
    #pragma unroll
    for (int r = 0; r < 4; ++r) {
        int grow = brow + w * 16 + qr * 4 + r;
        if (grow < M) {
            if (col == 0) {
                a_src[2 * grow + 0] = pS0[r];
                a_src[2 * grow + 1] = pS1[r];
                a_dst[2 * grow + 0] = pD0[r];
                a_dst[2 * grow + 1] = pD1[r];
            }
            #pragma unroll
            for (int ct = 0; ct < 4; ++ct)
                hb[(size_t)grow * 64 + ct * 16 + col] =
                    bf16pack(acc[ct][r], acc[ct + 4][r]);
        }
    }
}

// ---------------------------------------------------------------------------
// A1: per-chunk LDS histogram over NB buckets -> off[bucket][chunk] (counts)
// ---------------------------------------------------------------------------
__global__ __launch_bounds__(256) void k_hist(const int* __restrict__ ei_dst,
                                              int* __restrict__ off,
                                              int E, int NB, int PB) {
    __shared__ int hist[NBMAX];
    int pb = blockIdx.x, t = threadIdx.x;
    for (int i = t; i < NB; i += 256) hist[i] = 0;
    __syncthreads();
    int base = pb * CHUNK;
    int lim = E - base; if (lim > CHUNK) lim = CHUNK;
    for (int i = t; i < lim; i += 256)
        atomicAdd(&hist[ei_dst[base + i] >> 7], 1);
    __syncthreads();
    for (int i = t; i < NB; i += 256)
        off[(size_t)i * PB + pb] = hist[i];
}

// ---------------------------------------------------------------------------
// scan of off[] (n = NB*PB, bucket-major): 1024/block; block sums scanned in
// k_scan2; the bsum add is folded into the consumers (k_part/k_csr).
// ---------------------------------------------------------------------------
__global__ __launch_bounds__(256) void k_scan1(int* __restrict__ a,
                                               int* __restrict__ bsum, int n) {
    __shared__ int sm[256];
    int t = threadIdx.x;
    int base = blockIdx.x * 1024 + t * 4;
    int v0 = 0, v1 = 0, v2 = 0, v3 = 0;
    if (base + 0 < n) v0 = a[base + 0];
    if (base + 1 < n) v1 = a[base + 1];
    if (base + 2 < n) v2 = a[base + 2];
    if (base + 3 < n) v3 = a[base + 3];
    int s = v0 + v1 + v2 + v3;
    sm[t] = s;
    __syncthreads();
    for (int o = 1; o < 256; o <<= 1) {
        int u = (t >= o) ? sm[t - o] : 0;
        __syncthreads();
        sm[t] += u;
        __syncthreads();
    }
    int excl = sm[t] - s;
    if (base + 0 < n) a[base + 0] = excl;
    if (base + 1 < n) a[base + 1] = excl + v0;
    if (base + 2 < n) a[base + 2] = excl + v0 + v1;
    if (base + 3 < n) a[base + 3] = excl + v0 + v1 + v2;
    if (t == 255) bsum[blockIdx.x] = sm[255];
}

__global__ __launch_bounds__(512) void k_scan2(int* __restrict__ bsum, int nb) {
    __shared__ int sm[512];
    int t = threadIdx.x;
    int v = (t < nb) ? bsum[t] : 0;
    sm[t] = v;
    __syncthreads();
    for (int o = 1; o < 512; o <<= 1) {
        int u = (t >= o) ? sm[t - o] : 0;
        __syncthreads();
        sm[t] += u;
        __syncthreads();
    }
    if (t < nb) bsum[t] = sm[t] - v;
}

// ---------------------------------------------------------------------------
// A3: partition scatter. slot = off[bucket][chunk] + bsum + LDS rank.
// pA = {src | dst_local<<17, half2(ae0,ae1)}
// ---------------------------------------------------------------------------
__global__ __launch_bounds__(256) void k_part(const int* __restrict__ ei,
                                              const float* __restrict__ ea,
                                              const float* __restrict__ V,
                                              const int* __restrict__ off,
                                              const int* __restrict__ bsum,
                                              uint2* __restrict__ pA,
                                              int E, int NB, int PB) {
    __shared__ int cur[NBMAX];
    int pb = blockIdx.x, t = threadIdx.x;
    for (int i = t; i < NB; i += 256) {
        size_t oi = (size_t)i * PB + pb;
        cur[i] = off[oi] + bsum[oi >> 10];
    }
    __syncthreads();
    float v0 = V[0], v1 = V[1], v2 = V[2], v3 = V[3];
    float v4 = V[4], v5 = V[5], v6 = V[6], v7 = V[7];
    int base = pb * CHUNK;
    int lim = E - base; if (lim > CHUNK) lim = CHUNK;
    for (int i = t; i < lim; i += 256) {
        int e = base + i;
        int s = ei[e], d = ei[E + e];
        float4 a = ((const float4*)ea)[e];
        float ae0 = a.x * v0 + a.y * v2 + a.z * v4 + a.w * v6;
        float ae1 = a.x * v1 + a.y * v3 + a.z * v5 + a.w * v7;
        int slot = atomicAdd(&cur[d >> 7], 1);
        __half2 h = __floats2half2_rn(ae0, ae1);
        pA[slot] = make_uint2((unsigned)s | ((unsigned)(d & 127) << 17),
                              *reinterpret_cast<unsigned*>(&h));
    }
}

// ---------------------------------------------------------------------------
// B: per-bucket CSR build + alpha/exp. One block per bucket (128 nodes).
// ---------------------------------------------------------------------------
__global__ __launch_bounds__(256) void k_csr(const uint2* __restrict__ pA,
                                             const int* __restrict__ off,
                                             const int* __restrict__ bsum,
                                             const float* __restrict__ a_src,
                                             const float* __restrict__ a_dst,
                                             int* __restrict__ rowptr,
                                             uint2* __restrict__ payload,
                                             int M, int E, int NB, int PB) {
    __shared__ int cnt[128];
    __shared__ int sc[128];
    __shared__ int cur[128];
    __shared__ float2 adl[128];
    int b = blockIdx.x, t = threadIdx.x;
    int n0 = b << 7;
    int nloc = M - n0; if (nloc > 128) nloc = 128;
    size_t o0 = (size_t)b * PB;
    int s0 = off[o0] + bsum[o0 >> 10];
    int s1 = E;
    if (b + 1 < NB) {
        size_t o1 = (size_t)(b + 1) * PB;
        s1 = off[o1] + bsum[o1 >> 10];
    }
    if (t < 128) {
        cnt[t] = 0;
        if (t < nloc) adl[t] = ((const float2*)a_dst)[n0 + t];
    }
    __syncthreads();
    for (int i = s0 + t; i < s1; i += 256)
        atomicAdd(&cnt[(pA[i].x >> 17) & 127], 1);
    __syncthreads();
    if (t < 128) sc[t] = cnt[t];
    __syncthreads();
    for (int o = 1; o < 128; o <<= 1) {
        int u = 0;
        if (t < 128 && t >= o) u = sc[t - o];
        __syncthreads();
        if (t < 128) sc[t] += u;
        __syncthreads();
    }
    if (t < 128) {
        int base = s0 + sc[t] - cnt[t];
        cur[t] = base;
        if (t < nloc) rowptr[n0 + t] = base;
    }
    if (b == NB - 1 && t == 0) rowptr[M] = E;
    __syncthreads();
    for (int i = s0 + t; i < s1; i += 256) {
        uint2 p = pA[i];
        int src = p.x & 0x1FFFF;
        int dl = (p.x >> 17) & 127;
        __half2 aeh = *reinterpret_cast<__half2*>(&p.y);
        float ae0 = __low2float(aeh), ae1 = __high2float(aeh);
        float2 as = ((const float2*)a_src)[src];
        float2 ad = adl[dl];
        float al0 = as.x + ad.x + ae0; al0 = al0 > 0.f ? al0 : NEG_SLOPE * al0;
        float al1 = as.y + ad.y + ae1; al1 = al1 > 0.f ? al1 : NEG_SLOPE * al1;
        __half2 hx = __floats2half2_rn(__expf(al0), __expf(al1));
        int pos = atomicAdd(&cur[dl], 1);
        payload[pos] = make_uint2((unsigned)src, *reinterpret_cast<unsigned*>(&hx));
    }
}

// ---------------------------------------------------------------------------
// gather per node (wave per node, lane = channel). Payload tile staged in
// wave-private LDS -> uniform-address broadcast reads (no ds_bpermute);
// src readfirstlane'd -> SGPR-base hb loads. In-loop denominator; fused
// head-mean + bias + LayerNorm + ReLU.
// ---------------------------------------------------------------------------
__global__ __launch_bounds__(256) void k_gather(const uint2* __restrict__ payload,
                                                const int* __restrict__ rowptr,
                                                const unsigned* __restrict__ hb,
                                                const float* __restrict__ bias,
                                                const float* __restrict__ gamma,
                                                const float* __restrict__ beta,
                                                float* __restrict__ out, int M) {
    __shared__ uint2 stg[4][64];
    int w = threadIdx.x >> 6, lane = threadIdx.x & 63;
    int n = blockIdx.x * 4 + w;
    if (n >= M) return;
    int beg = rowptr[n], end = rowptr[n + 1];
    float acc0 = 0.f, acc1 = 0.f, pe0 = 0.f, pe1 = 0.f;

    for (int base = beg; base < end; base += 64) {
        int cnt = end - base; if (cnt > 64) cnt = 64;
        uint2 p = make_uint2(0u, 0u);
        if (lane < cnt) p = payload[base + lane];
        stg[w][lane] = p;
        {   // per-lane denominator contribution (0 for inactive lanes)
            __half2 he = *reinterpret_cast<__half2*>(&p.y);
            pe0 += __low2float(he);
            pe1 += __high2float(he);
        }
        int j = 0;
        for (; j + 4 <= cnt; j += 4) {
            uint2 q0 = stg[w][j + 0], q1 = stg[w][j + 1];
            uint2 q2 = stg[w][j + 2], q3 = stg[w][j + 3];
            int s0 = __builtin_amdgcn_readfirstlane((int)q0.x);
            int s1 = __builtin_amdgcn_readfirstlane((int)q1.x);
            int s2 = __builtin_amdgcn_readfirstlane((int)q2.x);
            int s3 = __builtin_amdgcn_readfirstlane((int)q3.x);
            unsigned h0 = (hb + (size_t)s0 * 64)[lane];
            unsigned h1 = (hb + (size_t)s1 * 64)[lane];
            unsigned h2 = (hb + (size_t)s2 * 64)[lane];
            unsigned h3 = (hb + (size_t)s3 * 64)[lane];
            __half2 e0 = *reinterpret_cast<__half2*>(&q0.y);
            __half2 e1 = *reinterpret_cast<__half2*>(&q1.y);
            __half2 e2 = *reinterpret_cast<__half2*>(&q2.y);
            __half2 e3 = *reinterpret_cast<__half2*>(&q3.y);
            acc0 += __low2float(e0)  * __uint_as_float(h0 << 16);
            acc1 += __high2float(e0) * __uint_as_float(h0 & 0xffff0000u);
            acc0 += __low2float(e1)  * __uint_as_float(h1 << 16);
            acc1 += __high2float(e1) * __uint_as_float(h1 & 0xffff0000u);
            acc0 += __low2float(e2)  * __uint_as_float(h2 << 16);
            acc1 += __high2float(e2) * __uint_as_float(h2 & 0xffff0000u);
            acc0 += __low2float(e3)  * __uint_as_float(h3 << 16);
            acc1 += __high2float(e3) * __uint_as_float(h3 & 0xffff0000u);
        }
        for (; j < cnt; ++j) {
            uint2 q0 = stg[w][j];
            int s0 = __builtin_amdgcn_readfirstlane((int)q0.x);
            unsigned h0 = (hb + (size_t)s0 * 64)[lane];
            __half2 e0 = *reinterpret_cast<__half2*>(&q0.y);
            acc0 += __low2float(e0)  * __uint_as_float(h0 << 16);
            acc1 += __high2float(e0) * __uint_as_float(h0 & 0xffff0000u);
        }
    }

    float d0 = pe0, d1 = pe1;
    #pragma unroll
    for (int m = 32; m; m >>= 1) {
        d0 += __shfl_xor(d0, m);
        d1 += __shfl_xor(d1, m);
    }

    float o = 0.5f * (acc0 / (d0 + 1e-16f) + acc1 / (d1 + 1e-16f)) + bias[lane];
    float mu = o;
    #pragma unroll
    for (int m = 32; m; m >>= 1) mu += __shfl_xor(mu, m);
    mu *= (1.f / 64.f);
    float c = o - mu;
    float v = c * c;
    #pragma unroll
    for (int m = 32; m; m >>= 1) v += __shfl_xor(v, m);
    v *= (1.f / 64.f);
    float y = c * rsqrtf(v + LN_EPS) * gamma[lane] + beta[lane];
    out[(size_t)n * OUT_C + lane] = fmaxf(y, 0.f);
}

// ---------------------------------------------------------------------------
extern "C" void kernel_launch(void* const* d_in, const int* in_sizes, int n_in,
                              void* d_out, int out_size, void* d_ws, size_t ws_size,
                              hipStream_t stream) {
    const float* x     = (const float*)d_in[0];
    const int*   ei    = (const int*)d_in[1];
    const float* ea    = (const float*)d_in[2];
    const float* W     = (const float*)d_in[3];
    const float* attS  = (const float*)d_in[4];
    const float* attD  = (const float*)d_in[5];
    const float* We    = (const float*)d_in[6];
    const float* attE  = (const float*)d_in[7];
    const float* bias  = (const float*)d_in[8];
    const float* gamma = (const float*)d_in[9];
    const float* beta  = (const float*)d_in[10];

    const int M  = in_sizes[0] / IN_C;        // 100000
    const int E  = in_sizes[1] / 2;           // 1600000
    const int NB = (M + 127) >> 7;            // 782 buckets
    const int PB = (E + CHUNK - 1) / CHUNK;   // 391 partition chunks
    const int nS = NB * PB;                   // 305762 offsets
    const int nb2 = (nS + 1023) / 1024;       // 299 scan blocks (<=512)
    const int GB = (M + 63) / 64;             // 1563 gemm blocks

    char* ws = (char*)d_ws;
    size_t woff = 0;
    auto alloc = [&](size_t bytes) -> void* {
        void* p = ws + woff;
        woff += (bytes + 255) & ~(size_t)255;
        return p;
    };
    unsigned*       hb     = (unsigned*)      alloc((size_t)M * 64 * 4);
    float*          a_src  = (float*)         alloc((size_t)M * 2 * 4);
    float*          a_dst  = (float*)         alloc((size_t)M * 2 * 4);
    int*            off    = (int*)           alloc((size_t)nS * 4);
    int*            bsum   = (int*)           alloc((size_t)nb2 * 4);
    int*            rowptr = (int*)           alloc((size_t)(M + 1) * 4);
    uint2*          pA     = (uint2*)         alloc((size_t)E * 8);
    uint2*          payload= (uint2*)         alloc((size_t)E * 8);
    unsigned short* WbfT   = (unsigned short*)alloc(128 * 128 * 2);
    float*          V      = (float*)         alloc(32);

    k_prep<<<9, 256, 0, stream>>>(W, We, attE, WbfT, V);
    k_hist<<<PB, 256, 0, stream>>>(ei + E, off, E, NB, PB);
    k_gemm<<<GB, 256, 0, stream>>>(x, WbfT, attS, attD, hb, a_src, a_dst, M);
    k_scan1<<<nb2, 256, 0, stream>>>(off, bsum, nS);
    k_scan2<<<1, 512, 0, stream>>>(bsum, nb2);
    k_part<<<PB, 256, 0, stream>>>(ei, ea, V, off, bsum, pA, E, NB, PB);
    k_csr<<<NB, 256, 0, stream>>>(pA, off, bsum, a_src, a_dst, rowptr, payload, M, E, NB, PB);
    k_gather<<<(M + 3) / 4, 256, 0, stream>>>(payload, rowptr, hb, bias, gamma, beta,
                                              (float*)d_out, M);
}